// Round 1
// baseline (1725.165 us; speedup 1.0000x reference)
//
#include <hip/hip_runtime.h>
#include <cmath>

#define NUM_BINS 8
#define C_OUT 64
#define R1 16
#define R2 16

// ---------------- winner scatter (last-write-wins == max voxel index) -------
__global__ void k_scatter_winner(const int* __restrict__ inv,
                                 const int* __restrict__ coords,
                                 int Nv, int* __restrict__ winner) {
    int v = blockIdx.x * 256 + threadIdx.x;
    if (v < Nv) {
        int u = inv[v];
        int b = coords[v * 4 + 1];
        atomicMax(&winner[u * 8 + b], v);
    }
}

// ---------------- compaction: count / scan / write ----------------
__global__ void k_count(const int* __restrict__ cnt, int U, int* __restrict__ bc) {
    int i = blockIdx.x * 256 + threadIdx.x;
    int s = (i < U && cnt[i] >= 2) ? 1 : 0;
    unsigned long long m = __ballot(s);
    __shared__ int wc[4];
    int lane = threadIdx.x & 63, w = threadIdx.x >> 6;
    if (lane == 0) wc[w] = __popcll(m);
    __syncthreads();
    if (threadIdx.x == 0) bc[blockIdx.x] = wc[0] + wc[1] + wc[2] + wc[3];
}

__global__ void k_scan(int* __restrict__ d, int n) {
    __shared__ int tmp[256];
    __shared__ int carry;
    int t = threadIdx.x;
    if (t == 0) carry = 0;
    __syncthreads();
    for (int base = 0; base < n; base += 256) {
        int i = base + t;
        int v = (i < n) ? d[i] : 0;
        tmp[t] = v;
        __syncthreads();
        for (int o = 1; o < 256; o <<= 1) {
            int add = (t >= o) ? tmp[t - o] : 0;
            __syncthreads();
            tmp[t] += add;
            __syncthreads();
        }
        int incl = tmp[t];
        if (i < n) d[i] = carry + incl - v;   // exclusive
        __syncthreads();
        if (t == 255) carry += tmp[255];
        __syncthreads();
    }
}

__global__ void k_write_sel(const int* __restrict__ cnt, int U,
                            const int* __restrict__ boff, int* __restrict__ sel) {
    int i = blockIdx.x * 256 + threadIdx.x;
    int s = (i < U && cnt[i] >= 2) ? 1 : 0;
    unsigned long long m = __ballot(s);
    __shared__ int wc[4];
    int lane = threadIdx.x & 63, w = threadIdx.x >> 6;
    if (lane == 0) wc[w] = __popcll(m);
    __syncthreads();
    int off = boff[blockIdx.x];
    for (int j = 0; j < w; j++) off += wc[j];
    if (s) sel[off + __popcll(m & ((1ull << lane) - 1ull))] = i;
}

// ---------------- fused featurize (upmlp + CBAM) + GEMM1 (512->256) --------
__global__ __launch_bounds__(256) void k_rows_gemm1(
    const float* __restrict__ vf, const int* __restrict__ winner,
    const int* __restrict__ sel,
    const float* __restrict__ up_w1, const float* __restrict__ up_b1,
    const float* __restrict__ up_w2, const float* __restrict__ up_b2,
    const float* __restrict__ ca_w1, const float* __restrict__ ca_w2,
    const float* __restrict__ sa_conv, const float* __restrict__ bs_w1,
    float* __restrict__ y1, int M)
{
    __shared__ float xs[R1][512];       // per-row flat: xs[r][c*8+b]
    __shared__ float feat[8][5];
    __shared__ float h1[8][32];
    __shared__ float cmean[64], cmax[64];
    __shared__ float hred[16];          // [0:8] mean-branch, [8:16] max-branch
    __shared__ float amean[8], amax[8], sag[8];

    int t = threadIdx.x;
    int m0 = blockIdx.x * R1;

    for (int r = 0; r < R1; ++r) {
        int m = m0 + r;
        if (m >= M) break;              // uniform across block
        int u = sel[m];
        if (t < 40) {
            int b = t / 5, k = t % 5;
            int w = winner[u * 8 + b];
            feat[b][k] = (w >= 0) ? vf[(size_t)w * 5 + k] : 0.0f;
        }
        __syncthreads();
        // mm1: (8,5)@(5,32) + b1, relu
        {
            int b = t >> 5, j = t & 31;
            float a = up_b1[j];
            #pragma unroll
            for (int k = 0; k < 5; k++) a += feat[b][k] * up_w1[k * 32 + j];
            h1[b][j] = fmaxf(a, 0.0f);
        }
        __syncthreads();
        // mm2: (8,32)@(32,64) + b2 -> xs[r][c*8+b] (transposed store = x[c][b])
        {
            int b = t >> 5, c0 = t & 31;
            #pragma unroll
            for (int cc = 0; cc < 2; cc++) {
                int c = c0 + cc * 32;
                float a = up_b2[c];
                #pragma unroll
                for (int k = 0; k < 32; k++) a += h1[b][k] * up_w2[k * 64 + c];
                xs[r][c * 8 + b] = a;
            }
        }
        __syncthreads();
        // channel attention: mean/max over bins
        if (t < 64) {
            float s = 0.0f, mx = -1e38f;
            #pragma unroll
            for (int b = 0; b < 8; b++) { float v = xs[r][t * 8 + b]; s += v; mx = fmaxf(mx, v); }
            cmean[t] = s * 0.125f; cmax[t] = mx;
        }
        __syncthreads();
        if (t < 16) {
            int j = t & 7;
            const float* src = (t < 8) ? cmean : cmax;
            float a = 0.0f;
            for (int c = 0; c < 64; c++) a += src[c] * ca_w1[c * 8 + j];
            hred[t] = fmaxf(a, 0.0f);
        }
        __syncthreads();
        if (t < 64) {
            float a = 0.0f;
            #pragma unroll
            for (int j = 0; j < 8; j++) a += (hred[j] + hred[8 + j]) * ca_w2[j * 64 + t];
            float ca = 1.0f / (1.0f + expf(-a));
            #pragma unroll
            for (int b = 0; b < 8; b++) xs[r][t * 8 + b] *= ca;
        }
        __syncthreads();
        // spatial attention: mean/max over channels per bin
        if (t < 8) {
            float s = 0.0f, mx = -1e38f;
            for (int c = 0; c < 64; c++) { float v = xs[r][c * 8 + t]; s += v; mx = fmaxf(mx, v); }
            amean[t] = s * (1.0f / 64.0f); amax[t] = mx;
        }
        __syncthreads();
        if (t < 8) {
            float a = 0.0f;
            #pragma unroll
            for (int k = 0; k < 7; k++) {
                int p = t + k - 3;
                if (p >= 0 && p < 8) a += amean[p] * sa_conv[k] + amax[p] * sa_conv[7 + k];
            }
            sag[t] = 1.0f / (1.0f + expf(-a));
        }
        __syncthreads();
        for (int i = t; i < 512; i += 256) xs[r][i] *= sag[i & 7];
        __syncthreads();
    }

    // GEMM1: y1[m][t] = sum_k xs[r][k] * bs_w1[k][t], thread t = output col
    int nr = M - m0; if (nr > R1) nr = R1;
    float acc[R1];
    #pragma unroll
    for (int r = 0; r < R1; r++) acc[r] = 0.0f;
    for (int k = 0; k < 512; k += 4) {
        float w0 = bs_w1[(k + 0) * 256 + t];
        float w1 = bs_w1[(k + 1) * 256 + t];
        float w2 = bs_w1[(k + 2) * 256 + t];
        float w3 = bs_w1[(k + 3) * 256 + t];
        #pragma unroll
        for (int r = 0; r < R1; r++) {
            const float4 f = *(const float4*)&xs[r][k];
            acc[r] += f.x * w0 + f.y * w1 + f.z * w2 + f.w * w3;
        }
    }
    for (int r = 0; r < nr; r++) y1[(size_t)(m0 + r) * 256 + t] = acc[r];
}

// ---------------- column stats (sum, sumsq) over M rows ----------------
__global__ void k_colstats(const float* __restrict__ y, int M, int C,
                           int rows_per_blk, float* __restrict__ ss) {
    int t = threadIdx.x;
    int c = t % C;
    int g = t / C;
    int ng = 256 / C;
    int r0 = blockIdx.x * rows_per_blk;
    int r1 = r0 + rows_per_blk; if (r1 > M) r1 = M;
    float s = 0.0f, q = 0.0f;
    for (int r = r0 + g; r < r1; r += ng) {
        float v = y[(size_t)r * C + c];
        s += v; q += v * v;
    }
    atomicAdd(&ss[c], s);
    atomicAdd(&ss[C + c], q);
}

__global__ void k_finalize(const float* __restrict__ ss, const float* __restrict__ g,
                           const float* __restrict__ b, int C, float invM,
                           float* __restrict__ scsh) {
    int c = threadIdx.x;
    if (c < C) {
        float mean = ss[c] * invM;
        float var  = ss[C + c] * invM - mean * mean;
        float inv  = rsqrtf(var + 0.001f);
        float sc   = g[c] * inv;
        scsh[c]     = sc;
        scsh[C + c] = b[c] - mean * sc;
    }
}

// ---------------- BN1 + relu + GEMM2 (256->64) ----------------
__global__ __launch_bounds__(256) void k_bn1_gemm2(
    const float* __restrict__ y1, const float* __restrict__ scsh1,
    const float* __restrict__ bs_w2, float* __restrict__ out, int M)
{
    __shared__ float wl[256 * 64];      // 64 KB
    __shared__ float yn[R2][256];       // 16 KB
    int t = threadIdx.x;
    for (int i = t; i < 256 * 64; i += 256) wl[i] = bs_w2[i];
    int m0 = blockIdx.x * R2;
    int nr = M - m0; if (nr > R2) nr = R2;
    for (int r = 0; r < nr; r++) {
        float v = y1[(size_t)(m0 + r) * 256 + t];
        yn[r][t] = fmaxf(v * scsh1[t] + scsh1[256 + t], 0.0f);
    }
    __syncthreads();
    int c = t & 63, g = t >> 6;
    for (int r = g; r < nr; r += 4) {
        float a = 0.0f;
        #pragma unroll 4
        for (int k = 0; k < 256; k++) a += yn[r][k] * wl[k * 64 + c];
        out[(size_t)(m0 + r) * 64 + c] = a;
    }
}

// ---------------- BN2 apply (in place on d_out) ----------------
__global__ void k_bn2_apply(float* __restrict__ out, const float* __restrict__ scsh2, int n) {
    int i = blockIdx.x * 256 + threadIdx.x;
    if (i < n) {
        int c = i & 63;
        out[i] = fmaxf(out[i] * scsh2[c] + scsh2[64 + c], 0.0f);
    }
}

extern "C" void kernel_launch(void* const* d_in, const int* in_sizes, int n_in,
                              void* d_out, int out_size, void* d_ws, size_t ws_size,
                              hipStream_t stream) {
    const float* vf     = (const float*)d_in[0];
    const int*   coords = (const int*)d_in[1];
    const int*   inv    = (const int*)d_in[3];
    const int*   cnt    = (const int*)d_in[4];
    const float* up_w1  = (const float*)d_in[5];
    const float* up_b1  = (const float*)d_in[6];
    const float* up_w2  = (const float*)d_in[7];
    const float* up_b2  = (const float*)d_in[8];
    const float* ca_w1  = (const float*)d_in[9];
    const float* ca_w2  = (const float*)d_in[10];
    const float* sa_conv= (const float*)d_in[11];
    const float* bs_w1  = (const float*)d_in[12];
    const float* bn1_g  = (const float*)d_in[13];
    const float* bn1_b  = (const float*)d_in[14];
    const float* bs_w2  = (const float*)d_in[15];
    const float* bn2_g  = (const float*)d_in[16];
    const float* bn2_b  = (const float*)d_in[17];

    int Nv = in_sizes[3];
    int U  = in_sizes[4];
    int M  = out_size / 64;
    float* out = (float*)d_out;

    char* ws = (char*)d_ws;
    auto alloc = [&](size_t bytes) -> char* {
        char* p = ws;
        ws += (bytes + 255) / 256 * 256;
        return p;
    };
    int nb = (U + 255) / 256;
    int*   winner = (int*)alloc((size_t)U * 8 * 4);
    int*   bc     = (int*)alloc((size_t)nb * 4);
    int*   sel    = (int*)alloc((size_t)M * 4);
    float* ss     = (float*)alloc(640 * 4);      // ss1[512] then ss2[128]
    float* scsh1  = (float*)alloc(512 * 4);
    float* scsh2  = (float*)alloc(128 * 4);
    float* y1     = (float*)alloc((size_t)M * 256 * 4);

    hipMemsetAsync(winner, 0xFF, (size_t)U * 8 * 4, stream);   // -1
    hipMemsetAsync(ss, 0, 640 * 4, stream);

    k_scatter_winner<<<(Nv + 255) / 256, 256, 0, stream>>>(inv, coords, Nv, winner);
    k_count<<<nb, 256, 0, stream>>>(cnt, U, bc);
    k_scan<<<1, 256, 0, stream>>>(bc, nb);
    k_write_sel<<<nb, 256, 0, stream>>>(cnt, U, bc, sel);

    k_rows_gemm1<<<(M + R1 - 1) / R1, 256, 0, stream>>>(
        vf, winner, sel, up_w1, up_b1, up_w2, up_b2,
        ca_w1, ca_w2, sa_conv, bs_w1, y1, M);

    k_colstats<<<(M + 255) / 256, 256, 0, stream>>>(y1, M, 256, 256, ss);
    k_finalize<<<1, 256, 0, stream>>>(ss, bn1_g, bn1_b, 256, 1.0f / (float)M, scsh1);

    k_bn1_gemm2<<<(M + R2 - 1) / R2, 256, 0, stream>>>(y1, scsh1, bs_w2, out, M);

    k_colstats<<<(M + 255) / 256, 256, 0, stream>>>(out, M, 64, 256, ss + 512);
    k_finalize<<<1, 256, 0, stream>>>(ss + 512, bn2_g, bn2_b, 64, 1.0f / (float)M, scsh2);

    k_bn2_apply<<<((size_t)M * 64 + 255) / 256, 256, 0, stream>>>(out, scsh2, (int)((size_t)M * 64));
}

// Round 2
// 679.057 us; speedup vs baseline: 2.5405x; 2.5405x over previous
//
#include <hip/hip_runtime.h>
#include <cmath>

typedef __attribute__((ext_vector_type(8))) short short8;
typedef __attribute__((ext_vector_type(4))) float f32x4;

__device__ __forceinline__ ushort f2b(float x) {
    union { float f; unsigned u; } v; v.f = x;
    unsigned r = v.u + 0x7FFFu + ((v.u >> 16) & 1u);
    return (ushort)(r >> 16);
}
__device__ __forceinline__ float b2f(ushort h) {
    union { unsigned u; float f; } v; v.u = ((unsigned)h) << 16; return v.f;
}
__device__ __forceinline__ float sigm(float x) { return 1.0f / (1.0f + __expf(-x)); }

// ---------------- winner scatter (last-write-wins == max voxel index) -------
__global__ void k_scatter_winner(const int* __restrict__ inv,
                                 const int* __restrict__ coords,
                                 int Nv, int* __restrict__ winner) {
    int v = blockIdx.x * 256 + threadIdx.x;
    if (v < Nv) {
        int u = inv[v];
        int b = coords[v * 4 + 1];
        atomicMax(&winner[u * 8 + b], v);
    }
}

// ---------------- compaction: count / scan / write ----------------
__global__ void k_count(const int* __restrict__ cnt, int U, int* __restrict__ bc) {
    int i = blockIdx.x * 256 + threadIdx.x;
    int s = (i < U && cnt[i] >= 2) ? 1 : 0;
    unsigned long long m = __ballot(s);
    __shared__ int wc[4];
    int lane = threadIdx.x & 63, w = threadIdx.x >> 6;
    if (lane == 0) wc[w] = __popcll(m);
    __syncthreads();
    if (threadIdx.x == 0) bc[blockIdx.x] = wc[0] + wc[1] + wc[2] + wc[3];
}

__global__ void k_scan(int* __restrict__ d, int n) {
    __shared__ int tmp[256];
    __shared__ int carry;
    int t = threadIdx.x;
    if (t == 0) carry = 0;
    __syncthreads();
    for (int base = 0; base < n; base += 256) {
        int i = base + t;
        int v = (i < n) ? d[i] : 0;
        tmp[t] = v;
        __syncthreads();
        for (int o = 1; o < 256; o <<= 1) {
            int add = (t >= o) ? tmp[t - o] : 0;
            __syncthreads();
            tmp[t] += add;
            __syncthreads();
        }
        int incl = tmp[t];
        if (i < n) d[i] = carry + incl - v;   // exclusive
        __syncthreads();
        if (t == 255) carry += tmp[255];
        __syncthreads();
    }
}

__global__ void k_write_sel(const int* __restrict__ cnt, int U,
                            const int* __restrict__ boff, int* __restrict__ sel) {
    int i = blockIdx.x * 256 + threadIdx.x;
    int s = (i < U && cnt[i] >= 2) ? 1 : 0;
    unsigned long long m = __ballot(s);
    __shared__ int wc[4];
    int lane = threadIdx.x & 63, w = threadIdx.x >> 6;
    if (lane == 0) wc[w] = __popcll(m);
    __syncthreads();
    int off = boff[blockIdx.x];
    for (int j = 0; j < w; j++) off += wc[j];
    if (s) sel[off + __popcll(m & ((1ull << lane) - 1ull))] = i;
}

// ---------------- cast + transpose weights to bf16 [N][K] -------------------
__global__ void k_prep_w(const float* __restrict__ w1, const float* __restrict__ w2,
                         ushort* __restrict__ w1t, ushort* __restrict__ w2t) {
    int i = blockIdx.x * 256 + threadIdx.x;
    if (i < 512 * 256) {
        int n = i >> 9, k = i & 511;
        w1t[i] = f2b(w1[k * 256 + n]);
    }
    int j = i - 512 * 256;
    if (j >= 0 && j < 256 * 64) {
        int n = j >> 8, k = j & 255;
        w2t[j] = f2b(w2[k * 64 + n]);
    }
}

// ---------------- featurize: upMLP + CBAM, row-parallel, bf16 out ----------
__global__ __launch_bounds__(256) void k_featurize(
    const float* __restrict__ vf, const int* __restrict__ winner,
    const int* __restrict__ sel,
    const float* __restrict__ up_w1, const float* __restrict__ up_b1,
    const float* __restrict__ up_w2, const float* __restrict__ up_b2,
    const float* __restrict__ ca_w1, const float* __restrict__ ca_w2,
    const float* __restrict__ sa_conv,
    ushort* __restrict__ xsg, int M)
{
    __shared__ float w1s[160], b1s[32], w2s[2048], b2s[64];
    __shared__ float caw1[512], caw2[512], sas[14];
    __shared__ int   iw[8][8];
    __shared__ float sfeat[8][8][5];
    __shared__ float h1s[8][8][32];
    __shared__ float xs[8][512];          // xs[r][c*8+b]
    __shared__ float cm[8][64], cx[8][64];
    __shared__ float hr[8][16];
    __shared__ float am[8][8], ax[8][8], sag[8][8];

    int t = threadIdx.x;
    int m0 = blockIdx.x * 8;
    int nr = M - m0; if (nr > 8) nr = 8;

    for (int i = t; i < 160; i += 256) w1s[i] = up_w1[i];
    if (t < 32) b1s[t] = up_b1[t];
    for (int i = t; i < 2048; i += 256) w2s[i] = up_w2[i];
    if (t < 64) b2s[t] = up_b2[t];
    for (int i = t; i < 512; i += 256) { caw1[i] = ca_w1[i]; caw2[i] = ca_w2[i]; }
    if (t < 14) sas[t] = sa_conv[t];
    if (t < 64) {
        int r = t >> 3, b = t & 7;
        iw[r][b] = (r < nr) ? winner[sel[m0 + r] * 8 + b] : -1;
    }
    __syncthreads();
    for (int i = t; i < 320; i += 256) {
        int r = i / 40, q = i % 40, b = q / 5, k = q % 5;
        int w = iw[r][b];
        sfeat[r][b][k] = (r < nr && w >= 0) ? vf[(size_t)w * 5 + k] : 0.0f;
    }
    __syncthreads();
    // mm1: (8b,5)@(5,32) + b1, relu — 2048 outputs
    for (int i = t; i < 2048; i += 256) {
        int r = i >> 8, b = (i >> 5) & 7, j = i & 31;
        float a = b1s[j];
        #pragma unroll
        for (int k = 0; k < 5; k++) a = fmaf(sfeat[r][b][k], w1s[k * 32 + j], a);
        h1s[r][b][j] = fmaxf(a, 0.0f);
    }
    __syncthreads();
    // mm2: (8b,32)@(32,64) + b2 — 4096 outputs, transposed store x[c][b]
    #pragma unroll
    for (int q = 0; q < 16; q++) {
        int i = q * 256 + t;
        int c = i & 63, b = (i >> 6) & 7, r = i >> 9;
        float a = b2s[c];
        #pragma unroll 8
        for (int k = 0; k < 32; k++) a = fmaf(h1s[r][b][k], w2s[k * 64 + c], a);
        xs[r][c * 8 + b] = a;
    }
    __syncthreads();
    // channel attention: mean/max over bins
    for (int i = t; i < 512; i += 256) {
        int r = i >> 6, c = i & 63;
        float s = 0.0f, mx = -1e38f;
        #pragma unroll
        for (int b = 0; b < 8; b++) { float v = xs[r][c * 8 + b]; s += v; mx = fmaxf(mx, v); }
        cm[r][c] = s * 0.125f; cx[r][c] = mx;
    }
    __syncthreads();
    if (t < 128) {
        int r = t >> 4, q = t & 15, j = q & 7;
        const float* src = (q < 8) ? cm[r] : cx[r];
        float a = 0.0f;
        for (int c = 0; c < 64; c++) a = fmaf(src[c], caw1[c * 8 + j], a);
        hr[r][q] = fmaxf(a, 0.0f);
    }
    __syncthreads();
    for (int i = t; i < 512; i += 256) {
        int r = i >> 6, c = i & 63;
        float a = 0.0f;
        #pragma unroll
        for (int j = 0; j < 8; j++) a = fmaf(hr[r][j] + hr[r][8 + j], caw2[j * 64 + c], a);
        float cav = sigm(a);
        #pragma unroll
        for (int b = 0; b < 8; b++) xs[r][c * 8 + b] *= cav;
    }
    __syncthreads();
    // spatial attention
    if (t < 64) {
        int r = t >> 3, b = t & 7;
        float s = 0.0f, mx = -1e38f;
        for (int c = 0; c < 64; c++) { float v = xs[r][c * 8 + b]; s += v; mx = fmaxf(mx, v); }
        am[r][b] = s * (1.0f / 64.0f); ax[r][b] = mx;
    }
    __syncthreads();
    if (t < 64) {
        int r = t >> 3, b = t & 7;
        float a = 0.0f;
        #pragma unroll
        for (int k = 0; k < 7; k++) {
            int p = b + k - 3;
            if (p >= 0 && p < 8) a += am[r][p] * sas[k] + ax[r][p] * sas[7 + k];
        }
        sag[r][b] = sigm(a);
    }
    __syncthreads();
    #pragma unroll
    for (int q = 0; q < 16; q++) {
        int i = q * 256 + t;
        int r = i >> 9, p = i & 511;
        if (r < nr) xsg[(size_t)(m0 + r) * 512 + p] = f2b(xs[r][p] * sag[r][p & 7]);
    }
}

// ---------------- GEMM1: xs(Mp,512) @ w1t(256,512)^T -> y1 bf16 (Mp,256) ----
__global__ __launch_bounds__(256) void k_gemm1(
    const ushort* __restrict__ A, const ushort* __restrict__ B,
    ushort* __restrict__ C, int Mp)
{
    __shared__ ushort As[128 * 64];
    __shared__ ushort Bs[128 * 64];
    int t = threadIdx.x;
    int m0 = (blockIdx.x >> 1) * 128;
    int n0 = (blockIdx.x & 1) * 128;
    int l = t & 63, w = t >> 6;
    int wr = w >> 1, wc = w & 1;
    int lr = l & 15, lk = (l >> 4) * 8;
    f32x4 acc[4][4];
    #pragma unroll
    for (int i = 0; i < 4; i++)
        #pragma unroll
        for (int j = 0; j < 4; j++) acc[i][j] = (f32x4){0.f, 0.f, 0.f, 0.f};

    for (int kt = 0; kt < 512; kt += 64) {
        __syncthreads();
        #pragma unroll
        for (int q = 0; q < 4; q++) {
            int idx = q * 256 + t;
            int row = idx >> 3, kc = (idx & 7) * 8;
            *(float4*)&As[idx * 8] = *(const float4*)&A[(size_t)(m0 + row) * 512 + kt + kc];
            *(float4*)&Bs[idx * 8] = *(const float4*)&B[(size_t)(n0 + row) * 512 + kt + kc];
        }
        __syncthreads();
        #pragma unroll
        for (int s = 0; s < 2; s++) {
            short8 av[4], bv[4];
            #pragma unroll
            for (int i = 0; i < 4; i++) av[i] = *(short8*)&As[(wr * 64 + i * 16 + lr) * 64 + s * 32 + lk];
            #pragma unroll
            for (int j = 0; j < 4; j++) bv[j] = *(short8*)&Bs[(wc * 64 + j * 16 + lr) * 64 + s * 32 + lk];
            #pragma unroll
            for (int i = 0; i < 4; i++)
                #pragma unroll
                for (int j = 0; j < 4; j++)
                    acc[i][j] = __builtin_amdgcn_mfma_f32_16x16x32_bf16(av[i], bv[j], acc[i][j], 0, 0, 0);
        }
    }
    int orow = m0 + wr * 64 + (l >> 4) * 4;
    int ocol = n0 + wc * 64 + lr;
    #pragma unroll
    for (int i = 0; i < 4; i++)
        #pragma unroll
        for (int j = 0; j < 4; j++)
            #pragma unroll
            for (int q = 0; q < 4; q++)
                C[(size_t)(orow + i * 16 + q) * 256 + ocol + j * 16] = f2b(acc[i][j][q]);
}

// ---------------- col stats over bf16 y1 (C=256) ----------------
__global__ void k_colstats256b(const ushort* __restrict__ y, int M, float* __restrict__ ss) {
    int t = threadIdx.x;
    int r0 = blockIdx.x * 256;
    int r1 = r0 + 256; if (r1 > M) r1 = M;
    float s = 0.0f, q = 0.0f;
    for (int r = r0; r < r1; r++) {
        float v = b2f(y[(size_t)r * 256 + t]);
        s += v; q += v * v;
    }
    atomicAdd(&ss[t], s);
    atomicAdd(&ss[256 + t], q);
}

// ---------------- generic col stats fp32 ----------------
__global__ void k_colstats(const float* __restrict__ y, int M, int C,
                           int rows_per_blk, float* __restrict__ ss) {
    int t = threadIdx.x;
    int c = t % C;
    int g = t / C;
    int ng = 256 / C;
    int r0 = blockIdx.x * rows_per_blk;
    int r1 = r0 + rows_per_blk; if (r1 > M) r1 = M;
    float s = 0.0f, q = 0.0f;
    for (int r = r0 + g; r < r1; r += ng) {
        float v = y[(size_t)r * C + c];
        s += v; q += v * v;
    }
    atomicAdd(&ss[c], s);
    atomicAdd(&ss[C + c], q);
}

__global__ void k_finalize(const float* __restrict__ ss, const float* __restrict__ g,
                           const float* __restrict__ b, int C, float invM,
                           float* __restrict__ scsh) {
    int c = threadIdx.x;
    if (c < C) {
        float mean = ss[c] * invM;
        float var  = ss[C + c] * invM - mean * mean;
        float inv  = rsqrtf(var + 0.001f);
        float sc   = g[c] * inv;
        scsh[c]     = sc;
        scsh[C + c] = b[c] - mean * sc;
    }
}

// ---------------- BN1 + relu, in place on bf16 y1 ----------------
__global__ __launch_bounds__(256) void k_ynorm(ushort* __restrict__ y,
                                               const float* __restrict__ scsh, int nvec) {
    __shared__ float s1[512];
    int t = threadIdx.x;
    for (int i = t; i < 512; i += 256) s1[i] = scsh[i];
    __syncthreads();
    int vid = blockIdx.x * 256 + t;
    if (vid < nvec) {
        size_t i = (size_t)vid * 8;
        uint4 v = *(const uint4*)&y[i];
        ushort* p = (ushort*)&v;
        int c0 = (int)(i & 255);
        #pragma unroll
        for (int j = 0; j < 8; j++) {
            float x = b2f(p[j]);
            x = fmaf(x, s1[c0 + j], s1[256 + c0 + j]);
            p[j] = f2b(fmaxf(x, 0.0f));
        }
        *(uint4*)&y[i] = v;
    }
}

// ---------------- GEMM2: ynorm(Mp,256) @ w2t(64,256)^T -> out fp32 (M,64) ---
__global__ __launch_bounds__(256) void k_gemm2(
    const ushort* __restrict__ A, const ushort* __restrict__ B,
    float* __restrict__ out, int M)
{
    __shared__ ushort As[128 * 64];
    __shared__ ushort Bs[64 * 64];
    int t = threadIdx.x;
    int m0 = blockIdx.x * 128;
    int l = t & 63, w = t >> 6;
    int wr = w >> 1, wc = w & 1;
    int lr = l & 15, lk = (l >> 4) * 8;
    f32x4 acc[4][2];
    #pragma unroll
    for (int i = 0; i < 4; i++)
        #pragma unroll
        for (int j = 0; j < 2; j++) acc[i][j] = (f32x4){0.f, 0.f, 0.f, 0.f};

    for (int kt = 0; kt < 256; kt += 64) {
        __syncthreads();
        #pragma unroll
        for (int q = 0; q < 4; q++) {
            int idx = q * 256 + t;
            int row = idx >> 3, kc = (idx & 7) * 8;
            *(float4*)&As[idx * 8] = *(const float4*)&A[(size_t)(m0 + row) * 256 + kt + kc];
        }
        #pragma unroll
        for (int q = 0; q < 2; q++) {
            int idx = q * 256 + t;
            int row = idx >> 3, kc = (idx & 7) * 8;
            *(float4*)&Bs[idx * 8] = *(const float4*)&B[(size_t)row * 256 + kt + kc];
        }
        __syncthreads();
        #pragma unroll
        for (int s = 0; s < 2; s++) {
            short8 av[4], bv[2];
            #pragma unroll
            for (int i = 0; i < 4; i++) av[i] = *(short8*)&As[(wr * 64 + i * 16 + lr) * 64 + s * 32 + lk];
            #pragma unroll
            for (int j = 0; j < 2; j++) bv[j] = *(short8*)&Bs[(wc * 32 + j * 16 + lr) * 64 + s * 32 + lk];
            #pragma unroll
            for (int i = 0; i < 4; i++)
                #pragma unroll
                for (int j = 0; j < 2; j++)
                    acc[i][j] = __builtin_amdgcn_mfma_f32_16x16x32_bf16(av[i], bv[j], acc[i][j], 0, 0, 0);
        }
    }
    int orow = m0 + wr * 64 + (l >> 4) * 4;
    int ocol = wc * 32 + lr;
    #pragma unroll
    for (int i = 0; i < 4; i++)
        #pragma unroll
        for (int j = 0; j < 2; j++)
            #pragma unroll
            for (int q = 0; q < 4; q++) {
                int rr = orow + i * 16 + q;
                if (rr < M) out[(size_t)rr * 64 + ocol + j * 16] = acc[i][j][q];
            }
}

// ---------------- BN2 apply (in place on d_out) ----------------
__global__ void k_bn2_apply(float* __restrict__ out, const float* __restrict__ scsh2, int n) {
    int i = blockIdx.x * 256 + threadIdx.x;
    if (i < n) {
        int c = i & 63;
        out[i] = fmaxf(out[i] * scsh2[c] + scsh2[64 + c], 0.0f);
    }
}

extern "C" void kernel_launch(void* const* d_in, const int* in_sizes, int n_in,
                              void* d_out, int out_size, void* d_ws, size_t ws_size,
                              hipStream_t stream) {
    const float* vf     = (const float*)d_in[0];
    const int*   coords = (const int*)d_in[1];
    const int*   inv    = (const int*)d_in[3];
    const int*   cnt    = (const int*)d_in[4];
    const float* up_w1  = (const float*)d_in[5];
    const float* up_b1  = (const float*)d_in[6];
    const float* up_w2  = (const float*)d_in[7];
    const float* up_b2  = (const float*)d_in[8];
    const float* ca_w1  = (const float*)d_in[9];
    const float* ca_w2  = (const float*)d_in[10];
    const float* sa_conv= (const float*)d_in[11];
    const float* bs_w1  = (const float*)d_in[12];
    const float* bn1_g  = (const float*)d_in[13];
    const float* bn1_b  = (const float*)d_in[14];
    const float* bs_w2  = (const float*)d_in[15];
    const float* bn2_g  = (const float*)d_in[16];
    const float* bn2_b  = (const float*)d_in[17];

    int Nv = in_sizes[3];
    int U  = in_sizes[4];
    int M  = out_size / 64;
    int Mp = (M + 127) & ~127;
    float* out = (float*)d_out;

    char* ws = (char*)d_ws;
    auto alloc = [&](size_t bytes) -> char* {
        char* p = ws;
        ws += (bytes + 255) / 256 * 256;
        return p;
    };
    int nb = (U + 255) / 256;
    int*    winner = (int*)alloc((size_t)U * 8 * 4);
    int*    bc     = (int*)alloc((size_t)nb * 4);
    int*    sel    = (int*)alloc((size_t)M * 4);
    float*  ss     = (float*)alloc(640 * 4);
    float*  scsh1  = (float*)alloc(512 * 4);
    float*  scsh2  = (float*)alloc(128 * 4);
    ushort* w1t    = (ushort*)alloc((size_t)512 * 256 * 2);
    ushort* w2t    = (ushort*)alloc((size_t)256 * 64 * 2);
    ushort* xsg    = (ushort*)alloc((size_t)Mp * 512 * 2);
    ushort* y1     = (ushort*)alloc((size_t)Mp * 256 * 2);

    hipMemsetAsync(winner, 0xFF, (size_t)U * 8 * 4, stream);
    hipMemsetAsync(ss, 0, 640 * 4, stream);
    if (Mp > M)
        hipMemsetAsync(xsg + (size_t)M * 512, 0, (size_t)(Mp - M) * 512 * 2, stream);

    k_prep_w<<<(512 * 256 + 256 * 64 + 255) / 256, 256, 0, stream>>>(bs_w1, bs_w2, w1t, w2t);
    k_scatter_winner<<<(Nv + 255) / 256, 256, 0, stream>>>(inv, coords, Nv, winner);
    k_count<<<nb, 256, 0, stream>>>(cnt, U, bc);
    k_scan<<<1, 256, 0, stream>>>(bc, nb);
    k_write_sel<<<nb, 256, 0, stream>>>(cnt, U, bc, sel);

    k_featurize<<<(M + 7) / 8, 256, 0, stream>>>(
        vf, winner, sel, up_w1, up_b1, up_w2, up_b2,
        ca_w1, ca_w2, sa_conv, xsg, M);

    k_gemm1<<<(Mp / 128) * 2, 256, 0, stream>>>(xsg, w1t, y1, Mp);

    k_colstats256b<<<(M + 255) / 256, 256, 0, stream>>>(y1, M, ss);
    k_finalize<<<1, 256, 0, stream>>>(ss, bn1_g, bn1_b, 256, 1.0f / (float)M, scsh1);

    k_ynorm<<<(Mp * 32 + 255) / 256, 256, 0, stream>>>(y1, scsh1, Mp * 32);

    k_gemm2<<<Mp / 128, 256, 0, stream>>>(y1, w2t, out, M);

    k_colstats<<<(M + 255) / 256, 256, 0, stream>>>(out, M, 64, 256, ss + 512);
    k_finalize<<<1, 256, 0, stream>>>(ss + 512, bn2_g, bn2_b, 64, 1.0f / (float)M, scsh2);

    k_bn2_apply<<<((size_t)M * 64 + 255) / 256, 256, 0, stream>>>(out, scsh2, (int)((size_t)M * 64));
}

// Round 3
// 509.033 us; speedup vs baseline: 3.3891x; 1.3340x over previous
//
#include <hip/hip_runtime.h>
#include <cmath>

typedef __attribute__((ext_vector_type(8))) short short8;
typedef __attribute__((ext_vector_type(4))) float f32x4;

__device__ __forceinline__ ushort f2b(float x) {
    union { float f; unsigned u; } v; v.f = x;
    unsigned r = v.u + 0x7FFFu + ((v.u >> 16) & 1u);
    return (ushort)(r >> 16);
}
__device__ __forceinline__ float b2f(ushort h) {
    union { unsigned u; float f; } v; v.u = ((unsigned)h) << 16; return v.f;
}
__device__ __forceinline__ float sigm(float x) { return 1.0f / (1.0f + __expf(-x)); }

// ---------------- winner scatter (last-write-wins == max voxel index) -------
__global__ void k_scatter_winner(const int* __restrict__ inv,
                                 const int* __restrict__ coords,
                                 int Nv, int* __restrict__ winner) {
    int v = blockIdx.x * 256 + threadIdx.x;
    if (v < Nv) {
        int u = inv[v];
        int b = coords[v * 4 + 1];
        atomicMax(&winner[u * 8 + b], v);
    }
}

// ---------------- compaction: count / scan / write ----------------
__global__ void k_count(const int* __restrict__ cnt, int U, int* __restrict__ bc) {
    int i = blockIdx.x * 256 + threadIdx.x;
    int s = (i < U && cnt[i] >= 2) ? 1 : 0;
    unsigned long long m = __ballot(s);
    __shared__ int wc[4];
    int lane = threadIdx.x & 63, w = threadIdx.x >> 6;
    if (lane == 0) wc[w] = __popcll(m);
    __syncthreads();
    if (threadIdx.x == 0) bc[blockIdx.x] = wc[0] + wc[1] + wc[2] + wc[3];
}

__global__ void k_scan_wave(int* __restrict__ d, int n) {   // 1 block, 64 threads
    int l = threadIdx.x;
    int carry = 0;
    for (int base = 0; base < n; base += 64) {
        int v = (base + l < n) ? d[base + l] : 0;
        int s = v;
        #pragma unroll
        for (int o = 1; o < 64; o <<= 1) {
            int q = __shfl_up(s, o);
            if (l >= o) s += q;
        }
        if (base + l < n) d[base + l] = carry + s - v;   // exclusive
        carry += __shfl(s, 63);
    }
}

__global__ void k_write_sel(const int* __restrict__ cnt, int U,
                            const int* __restrict__ boff, int* __restrict__ sel) {
    int i = blockIdx.x * 256 + threadIdx.x;
    int s = (i < U && cnt[i] >= 2) ? 1 : 0;
    unsigned long long m = __ballot(s);
    __shared__ int wc[4];
    int lane = threadIdx.x & 63, w = threadIdx.x >> 6;
    if (lane == 0) wc[w] = __popcll(m);
    __syncthreads();
    int off = boff[blockIdx.x];
    for (int j = 0; j < w; j++) off += wc[j];
    if (s) sel[off + __popcll(m & ((1ull << lane) - 1ull))] = i;
}

// ---------------- cast + transpose weights to bf16 [N][K] -------------------
__global__ void k_prep_w(const float* __restrict__ w1, const float* __restrict__ w2,
                         ushort* __restrict__ w1t, ushort* __restrict__ w2t) {
    int i = blockIdx.x * 256 + threadIdx.x;
    if (i < 512 * 256) {
        int n = i >> 9, k = i & 511;
        w1t[i] = f2b(w1[k * 256 + n]);
    }
    int j = i - 512 * 256;
    if (j >= 0 && j < 256 * 64) {
        int n = j >> 8, k = j & 255;
        w2t[j] = f2b(w2[k * 64 + n]);
    }
}

// ---------------- featurize v3: one wave per row, x in registers ------------
__global__ __launch_bounds__(64) void k_feat3(
    const float* __restrict__ vf, const int* __restrict__ winner,
    const int* __restrict__ sel,
    const float* __restrict__ up_w1, const float* __restrict__ up_b1,
    const float* __restrict__ up_w2, const float* __restrict__ up_b2,
    const float* __restrict__ ca_w1, const float* __restrict__ ca_w2,
    const float* __restrict__ sa_conv,
    ushort* __restrict__ xsg, int M, int nw)
{
    __shared__ float sfeat[64];     // [b*8+k], k<5 used
    __shared__ float h1[256];       // [b*32+k]
    __shared__ float cma[144];      // [branch*72 + c]  (72-stride: conflict-free)
    __shared__ float xsl[520];      // [b*65 + c]       (65-stride: conflict-free)

    int l = threadIdx.x;
    int c = l;                                   // lane <-> channel
    // ---- per-wave weight preloads (row-invariant) ----
    float w2col[32];
    #pragma unroll
    for (int k = 0; k < 32; k++) w2col[k] = up_w2[k * 64 + c];
    float b2v = up_b2[c];
    int jm1 = l & 31;
    float w1v[5];
    #pragma unroll
    for (int k = 0; k < 5; k++) w1v[k] = up_w1[k * 32 + jm1];
    float b1v = up_b1[jm1];
    int jj = l & 15, cg = l >> 4, jca = jj & 7, br = jj >> 3;
    float caw1v[16];
    #pragma unroll
    for (int i = 0; i < 16; i++) caw1v[i] = ca_w1[(cg * 16 + i) * 8 + jca];
    float caw2v[8];
    #pragma unroll
    for (int j = 0; j < 8; j++) caw2v[j] = ca_w2[j * 64 + c];
    float sas[14];
    #pragma unroll
    for (int k = 0; k < 14; k++) sas[k] = sa_conv[k];
    int bsa = l & 7, cgs = l >> 3;
    int b40 = l / 5, k40 = l - b40 * 5;

    int iters = (M + nw - 1) / nw;
    for (int it = 0; it < iters; ++it) {
        int m = blockIdx.x + it * nw;
        bool act = (m < M);
        // ---- gather feat (40 values) ----
        int wv = -1;
        if (act) {
            int u = sel[m];
            if (l < 8) wv = winner[u * 8 + l];
        }
        int wl = __shfl(wv, b40);
        float fv = 0.0f;
        if (act && l < 40 && wl >= 0) fv = vf[(size_t)wl * 5 + k40];
        if (l < 40) sfeat[b40 * 8 + k40] = fv;
        __syncthreads();
        // ---- mm1: h1[b][j] = relu(feat[b] @ w1 + b1) ----
        #pragma unroll
        for (int i = 0; i < 4; i++) {
            int b = (l >> 5) * 4 + i;
            const float4 f4 = *(const float4*)&sfeat[b * 8];
            float a = b1v;
            a = fmaf(f4.x, w1v[0], a);
            a = fmaf(f4.y, w1v[1], a);
            a = fmaf(f4.z, w1v[2], a);
            a = fmaf(f4.w, w1v[3], a);
            a = fmaf(sfeat[b * 8 + 4], w1v[4], a);
            h1[b * 32 + jm1] = fmaxf(a, 0.0f);
        }
        __syncthreads();
        // ---- mm2: x[b] = b2[c] + h1[b] @ w2col (broadcast b128 reads) ----
        float x[8];
        #pragma unroll
        for (int b = 0; b < 8; b++) {
            float a = b2v;
            #pragma unroll
            for (int kq = 0; kq < 8; kq++) {
                const float4 h4 = *(const float4*)&h1[b * 32 + kq * 4];
                a = fmaf(h4.x, w2col[kq * 4 + 0], a);
                a = fmaf(h4.y, w2col[kq * 4 + 1], a);
                a = fmaf(h4.z, w2col[kq * 4 + 2], a);
                a = fmaf(h4.w, w2col[kq * 4 + 3], a);
            }
            x[b] = a;
        }
        // ---- channel attention ----
        float cmv = 0.f, cxv = -1e38f;
        #pragma unroll
        for (int b = 0; b < 8; b++) { cmv += x[b]; cxv = fmaxf(cxv, x[b]); }
        cma[c] = cmv * 0.125f;
        cma[72 + c] = cxv;
        __syncthreads();
        float part = 0.0f;
        const float* srcb = &cma[br * 72 + cg * 16];
        #pragma unroll
        for (int i = 0; i < 16; i++) part = fmaf(srcb[i], caw1v[i], part);
        part += __shfl_xor(part, 16);
        part += __shfl_xor(part, 32);
        float hr = fmaxf(part, 0.0f);
        float hsum = hr + __shfl_xor(hr, 8);       // mean-branch + max-branch
        float aca = 0.0f;
        #pragma unroll
        for (int j = 0; j < 8; j++) aca = fmaf(__shfl(hsum, j), caw2v[j], aca);
        float cav = sigm(aca);
        #pragma unroll
        for (int b = 0; b < 8; b++) x[b] *= cav;
        __syncthreads();
        // ---- spatial attention (LDS transpose, pad-65) ----
        #pragma unroll
        for (int b = 0; b < 8; b++) xsl[b * 65 + c] = x[b];
        __syncthreads();
        float s = 0.f, mxv = -1e38f;
        #pragma unroll
        for (int i = 0; i < 8; i++) {
            float v = xsl[bsa * 65 + cgs * 8 + i];
            s += v; mxv = fmaxf(mxv, v);
        }
        s += __shfl_xor(s, 8);  mxv = fmaxf(mxv, __shfl_xor(mxv, 8));
        s += __shfl_xor(s, 16); mxv = fmaxf(mxv, __shfl_xor(mxv, 16));
        s += __shfl_xor(s, 32); mxv = fmaxf(mxv, __shfl_xor(mxv, 32));
        float am = s * (1.0f / 64.0f);
        float aconv = 0.0f;
        #pragma unroll
        for (int k = 0; k < 7; k++) {
            int p = bsa + k - 3;
            int sl = (l & 56) | (p & 7);
            float amp = __shfl(am, sl);
            float axp = __shfl(mxv, sl);
            if (p >= 0 && p < 8) aconv += amp * sas[k] + axp * sas[7 + k];
        }
        float sg = sigm(aconv);
        // ---- apply SA gate + pack + store (one 16B store per lane) ----
        unsigned xb[4];
        #pragma unroll
        for (int b = 0; b < 8; b += 2) {
            float sg0 = __shfl(sg, b);
            float sg1 = __shfl(sg, b + 1);
            unsigned lo = f2b(x[b] * sg0);
            unsigned hi = f2b(x[b + 1] * sg1);
            xb[b >> 1] = lo | (hi << 16);
        }
        if (act) {
            uint4 pk = make_uint4(xb[0], xb[1], xb[2], xb[3]);
            *(uint4*)&xsg[(size_t)m * 512 + c * 8] = pk;
        }
        __syncthreads();
    }
}

// ---------------- GEMM1 (swizzled LDS) + fused BN1 column stats -------------
__global__ __launch_bounds__(256) void k_gemm1(
    const ushort* __restrict__ A, const ushort* __restrict__ B,
    ushort* __restrict__ C, float* __restrict__ ss, int Mp)
{
    __shared__ ushort As[128 * 64];
    __shared__ ushort Bs[128 * 64];
    int t = threadIdx.x;
    int m0 = (blockIdx.x >> 1) * 128;
    int n0 = (blockIdx.x & 1) * 128;
    int l = t & 63, w = t >> 6;
    int wr = w >> 1, wc = w & 1;
    int lr = l & 15, lg = l >> 4, lk = lg * 8;
    f32x4 acc[4][4];
    #pragma unroll
    for (int i = 0; i < 4; i++)
        #pragma unroll
        for (int j = 0; j < 4; j++) acc[i][j] = (f32x4){0.f, 0.f, 0.f, 0.f};

    for (int kt = 0; kt < 512; kt += 64) {
        __syncthreads();
        #pragma unroll
        for (int q = 0; q < 4; q++) {
            int idx = q * 256 + t;
            int row = idx >> 3, kc = (idx & 7) * 8;
            int sk = kc ^ ((row & 7) << 3);
            uint4 av = *(const uint4*)&A[(size_t)(m0 + row) * 512 + kt + kc];
            uint4 bv = *(const uint4*)&B[(size_t)(n0 + row) * 512 + kt + kc];
            *(uint4*)&As[row * 64 + sk] = av;
            *(uint4*)&Bs[row * 64 + sk] = bv;
        }
        __syncthreads();
        #pragma unroll
        for (int s = 0; s < 2; s++) {
            short8 av[4], bv[4];
            #pragma unroll
            for (int i = 0; i < 4; i++) {
                int row = wr * 64 + i * 16 + lr;
                av[i] = *(short8*)&As[row * 64 + ((s * 32 + lk) ^ ((row & 7) << 3))];
            }
            #pragma unroll
            for (int j = 0; j < 4; j++) {
                int row = wc * 64 + j * 16 + lr;
                bv[j] = *(short8*)&Bs[row * 64 + ((s * 32 + lk) ^ ((row & 7) << 3))];
            }
            #pragma unroll
            for (int i = 0; i < 4; i++)
                #pragma unroll
                for (int j = 0; j < 4; j++)
                    acc[i][j] = __builtin_amdgcn_mfma_f32_16x16x32_bf16(av[i], bv[j], acc[i][j], 0, 0, 0);
        }
    }
    int orow = m0 + wr * 64 + lg * 4;
    int ocol = n0 + wc * 64 + lr;
    float csum[4], csq[4];
    #pragma unroll
    for (int j = 0; j < 4; j++) { csum[j] = 0.f; csq[j] = 0.f; }
    #pragma unroll
    for (int i = 0; i < 4; i++)
        #pragma unroll
        for (int j = 0; j < 4; j++)
            #pragma unroll
            for (int q = 0; q < 4; q++) {
                float v = acc[i][j][q];
                C[(size_t)(orow + i * 16 + q) * 256 + ocol + j * 16] = f2b(v);
                csum[j] += v; csq[j] += v * v;
            }
    #pragma unroll
    for (int j = 0; j < 4; j++) {
        csum[j] += __shfl_xor(csum[j], 16); csum[j] += __shfl_xor(csum[j], 32);
        csq[j]  += __shfl_xor(csq[j], 16);  csq[j]  += __shfl_xor(csq[j], 32);
    }
    if (l < 16) {
        #pragma unroll
        for (int j = 0; j < 4; j++) {
            atomicAdd(&ss[ocol + j * 16], csum[j]);
            atomicAdd(&ss[256 + ocol + j * 16], csq[j]);
        }
    }
}

__global__ void k_finalize(const float* __restrict__ ss, const float* __restrict__ g,
                           const float* __restrict__ b, int C, float invM,
                           float* __restrict__ scsh) {
    int c = threadIdx.x;
    if (c < C) {
        float mean = ss[c] * invM;
        float var  = ss[C + c] * invM - mean * mean;
        float inv  = rsqrtf(var + 0.001f);
        float sc   = g[c] * inv;
        scsh[c]     = sc;
        scsh[C + c] = b[c] - mean * sc;
    }
}

// ---------- GEMM2: BN1+relu fused in A-staging; BN2 stats fused epilogue ----
__global__ __launch_bounds__(256) void k_gemm2(
    const ushort* __restrict__ A, const ushort* __restrict__ B,
    const float* __restrict__ scsh1,
    float* __restrict__ out, float* __restrict__ ss2, int M)
{
    __shared__ ushort As[128 * 64];
    __shared__ ushort Bs[64 * 64];
    __shared__ float s1[512];
    int t = threadIdx.x;
    for (int i = t; i < 512; i += 256) s1[i] = scsh1[i];
    int m0 = blockIdx.x * 128;
    int l = t & 63, w = t >> 6;
    int wr = w >> 1, wc = w & 1;
    int lr = l & 15, lg = l >> 4, lk = lg * 8;
    f32x4 acc[4][2];
    #pragma unroll
    for (int i = 0; i < 4; i++)
        #pragma unroll
        for (int j = 0; j < 2; j++) acc[i][j] = (f32x4){0.f, 0.f, 0.f, 0.f};

    for (int kt = 0; kt < 256; kt += 64) {
        __syncthreads();
        #pragma unroll
        for (int q = 0; q < 4; q++) {
            int idx = q * 256 + t;
            int row = idx >> 3, kc = (idx & 7) * 8;
            uint4 av = *(const uint4*)&A[(size_t)(m0 + row) * 256 + kt + kc];
            ushort* ap = (ushort*)&av;
            uint4 pk;
            unsigned* pkp = (unsigned*)&pk;
            #pragma unroll
            for (int h = 0; h < 4; h++) {
                int k0 = kt + kc + 2 * h;
                float v0 = fmaxf(fmaf(b2f(ap[2*h]),   s1[k0],   s1[256 + k0]),   0.f);
                float v1 = fmaxf(fmaf(b2f(ap[2*h+1]), s1[k0+1], s1[256 + k0+1]), 0.f);
                pkp[h] = (unsigned)f2b(v0) | ((unsigned)f2b(v1) << 16);
            }
            *(uint4*)&As[row * 64 + (kc ^ ((row & 7) << 3))] = pk;
        }
        #pragma unroll
        for (int q = 0; q < 2; q++) {
            int idx = q * 256 + t;
            int row = idx >> 3, kc = (idx & 7) * 8;
            uint4 bv = *(const uint4*)&B[(size_t)row * 256 + kt + kc];
            *(uint4*)&Bs[row * 64 + (kc ^ ((row & 7) << 3))] = bv;
        }
        __syncthreads();
        #pragma unroll
        for (int s = 0; s < 2; s++) {
            short8 av[4], bv[2];
            #pragma unroll
            for (int i = 0; i < 4; i++) {
                int row = wr * 64 + i * 16 + lr;
                av[i] = *(short8*)&As[row * 64 + ((s * 32 + lk) ^ ((row & 7) << 3))];
            }
            #pragma unroll
            for (int j = 0; j < 2; j++) {
                int row = wc * 32 + j * 16 + lr;
                bv[j] = *(short8*)&Bs[row * 64 + ((s * 32 + lk) ^ ((row & 7) << 3))];
            }
            #pragma unroll
            for (int i = 0; i < 4; i++)
                #pragma unroll
                for (int j = 0; j < 2; j++)
                    acc[i][j] = __builtin_amdgcn_mfma_f32_16x16x32_bf16(av[i], bv[j], acc[i][j], 0, 0, 0);
        }
    }
    int orow = m0 + wr * 64 + lg * 4;
    int ocol = wc * 32 + lr;
    float csum[2], csq[2];
    #pragma unroll
    for (int j = 0; j < 2; j++) { csum[j] = 0.f; csq[j] = 0.f; }
    #pragma unroll
    for (int i = 0; i < 4; i++)
        #pragma unroll
        for (int j = 0; j < 2; j++)
            #pragma unroll
            for (int q = 0; q < 4; q++) {
                int rr = orow + i * 16 + q;
                if (rr < M) {
                    float v = acc[i][j][q];
                    out[(size_t)rr * 64 + ocol + j * 16] = v;
                    csum[j] += v; csq[j] += v * v;
                }
            }
    #pragma unroll
    for (int j = 0; j < 2; j++) {
        csum[j] += __shfl_xor(csum[j], 16); csum[j] += __shfl_xor(csum[j], 32);
        csq[j]  += __shfl_xor(csq[j], 16);  csq[j]  += __shfl_xor(csq[j], 32);
    }
    if (l < 16) {
        #pragma unroll
        for (int j = 0; j < 2; j++) {
            atomicAdd(&ss2[ocol + j * 16], csum[j]);
            atomicAdd(&ss2[64 + ocol + j * 16], csq[j]);
        }
    }
}

// ---------------- BN2 apply (in place on d_out, float4) ----------------
__global__ void k_bn2_apply4(float4* __restrict__ out4, const float* __restrict__ scsh2, int n4) {
    int i = blockIdx.x * 256 + threadIdx.x;
    if (i < n4) {
        float4 v = out4[i];
        int c0 = (i & 15) * 4;
        v.x = fmaxf(fmaf(v.x, scsh2[c0 + 0], scsh2[64 + c0 + 0]), 0.f);
        v.y = fmaxf(fmaf(v.y, scsh2[c0 + 1], scsh2[64 + c0 + 1]), 0.f);
        v.z = fmaxf(fmaf(v.z, scsh2[c0 + 2], scsh2[64 + c0 + 2]), 0.f);
        v.w = fmaxf(fmaf(v.w, scsh2[c0 + 3], scsh2[64 + c0 + 3]), 0.f);
        out4[i] = v;
    }
}

extern "C" void kernel_launch(void* const* d_in, const int* in_sizes, int n_in,
                              void* d_out, int out_size, void* d_ws, size_t ws_size,
                              hipStream_t stream) {
    const float* vf     = (const float*)d_in[0];
    const int*   coords = (const int*)d_in[1];
    const int*   inv    = (const int*)d_in[3];
    const int*   cnt    = (const int*)d_in[4];
    const float* up_w1  = (const float*)d_in[5];
    const float* up_b1  = (const float*)d_in[6];
    const float* up_w2  = (const float*)d_in[7];
    const float* up_b2  = (const float*)d_in[8];
    const float* ca_w1  = (const float*)d_in[9];
    const float* ca_w2  = (const float*)d_in[10];
    const float* sa_conv= (const float*)d_in[11];
    const float* bs_w1  = (const float*)d_in[12];
    const float* bn1_g  = (const float*)d_in[13];
    const float* bn1_b  = (const float*)d_in[14];
    const float* bs_w2  = (const float*)d_in[15];
    const float* bn2_g  = (const float*)d_in[16];
    const float* bn2_b  = (const float*)d_in[17];

    int Nv = in_sizes[3];
    int U  = in_sizes[4];
    int M  = out_size / 64;
    int Mp = (M + 127) & ~127;
    float* out = (float*)d_out;

    char* ws = (char*)d_ws;
    auto alloc = [&](size_t bytes) -> char* {
        char* p = ws;
        ws += (bytes + 255) / 256 * 256;
        return p;
    };
    int nb = (U + 255) / 256;
    int*    winner = (int*)alloc((size_t)U * 8 * 4);
    int*    bc     = (int*)alloc((size_t)nb * 4);
    int*    sel    = (int*)alloc((size_t)M * 4);
    float*  ss     = (float*)alloc(640 * 4);     // ss1[512] then ss2[128]
    float*  scsh1  = (float*)alloc(512 * 4);
    float*  scsh2  = (float*)alloc(128 * 4);
    ushort* w1t    = (ushort*)alloc((size_t)512 * 256 * 2);
    ushort* w2t    = (ushort*)alloc((size_t)256 * 64 * 2);
    ushort* xsg    = (ushort*)alloc((size_t)Mp * 512 * 2);
    ushort* y1     = (ushort*)alloc((size_t)Mp * 256 * 2);

    hipMemsetAsync(winner, 0xFF, (size_t)U * 8 * 4, stream);
    hipMemsetAsync(ss, 0, 640 * 4, stream);
    if (Mp > M)
        hipMemsetAsync(xsg + (size_t)M * 512, 0, (size_t)(Mp - M) * 512 * 2, stream);

    k_prep_w<<<(512 * 256 + 256 * 64 + 255) / 256, 256, 0, stream>>>(bs_w1, bs_w2, w1t, w2t);
    k_scatter_winner<<<(Nv + 255) / 256, 256, 0, stream>>>(inv, coords, Nv, winner);
    k_count<<<nb, 256, 0, stream>>>(cnt, U, bc);
    k_scan_wave<<<1, 64, 0, stream>>>(bc, nb);
    k_write_sel<<<nb, 256, 0, stream>>>(cnt, U, bc, sel);

    int nwf = 4096;
    k_feat3<<<nwf, 64, 0, stream>>>(
        vf, winner, sel, up_w1, up_b1, up_w2, up_b2,
        ca_w1, ca_w2, sa_conv, xsg, M, nwf);

    k_gemm1<<<(Mp / 128) * 2, 256, 0, stream>>>(xsg, w1t, y1, ss, Mp);
    k_finalize<<<1, 256, 0, stream>>>(ss, bn1_g, bn1_b, 256, 1.0f / (float)M, scsh1);

    k_gemm2<<<Mp / 128, 256, 0, stream>>>(y1, w2t, scsh1, out, ss + 512, M);
    k_finalize<<<1, 64, 0, stream>>>(ss + 512, bn2_g, bn2_b, 64, 1.0f / (float)M, scsh2);

    int n4 = (M * 64) / 4;
    k_bn2_apply4<<<(n4 + 255) / 256, 256, 0, stream>>>((float4*)out, scsh2, n4);
}

// Round 5
// 415.192 us; speedup vs baseline: 4.1551x; 1.2260x over previous
//
#include <hip/hip_runtime.h>
#include <cmath>

typedef __attribute__((ext_vector_type(8))) short short8;
typedef __attribute__((ext_vector_type(4))) float f32x4;

__device__ __forceinline__ ushort f2b(float x) {
    union { float f; unsigned u; } v; v.f = x;
    unsigned r = v.u + 0x7FFFu + ((v.u >> 16) & 1u);
    return (ushort)(r >> 16);
}
__device__ __forceinline__ float b2f(ushort h) {
    union { unsigned u; float f; } v; v.u = ((unsigned)h) << 16; return v.f;
}
__device__ __forceinline__ float sigm(float x) { return 1.0f / (1.0f + __expf(-x)); }

// ---- DPP helpers: 16-lane reductions on the VALU pipe (0 LDS ops) ----------
template <int C>
__device__ __forceinline__ float dppf(float x) {
    return __builtin_bit_cast(float,
        __builtin_amdgcn_update_dpp(0, __builtin_bit_cast(int, x), C, 0xf, 0xf, true));
}
__device__ __forceinline__ float rsum16(float v) {
    v += dppf<0x140>(v);   // row_mirror
    v += dppf<0x141>(v);   // row_half_mirror
    v += dppf<0x1B>(v);    // quad reverse
    v += dppf<0xB1>(v);    // quad xor1
    return v;
}
__device__ __forceinline__ float rmax16(float v) {
    v = fmaxf(v, dppf<0x140>(v));
    v = fmaxf(v, dppf<0x141>(v));
    v = fmaxf(v, dppf<0x1B>(v));
    v = fmaxf(v, dppf<0xB1>(v));
    return v;
}
__device__ __forceinline__ float swzf16(float x) {   // lane ^ 16
    return __builtin_bit_cast(float,
        __builtin_amdgcn_ds_swizzle(__builtin_bit_cast(int, x), 0x401F));
}
__device__ __forceinline__ unsigned swzu16(unsigned x) {
    return (unsigned)__builtin_amdgcn_ds_swizzle((int)x, 0x401F);
}

// ---- async global->LDS, 16B, linear dest (source carries inverse swizzle) --
#define GL16(g, s) __builtin_amdgcn_global_load_lds( \
    (const __attribute__((address_space(1))) unsigned int*)(g), \
    (__attribute__((address_space(3))) unsigned int*)(s), 16, 0, 0)

// ---------------- winner scatter (last-write-wins == max voxel index) -------
__global__ void k_scatter_winner(const int* __restrict__ inv,
                                 const int* __restrict__ coords,
                                 int Nv, int* __restrict__ winner) {
    int v = blockIdx.x * 256 + threadIdx.x;
    if (v < Nv) {
        int u = inv[v];
        int b = coords[v * 4 + 1];
        atomicMax(&winner[u * 8 + b], v);
    }
}

// ---------------- compaction: count / scan / write ----------------
__global__ void k_count(const int* __restrict__ cnt, int U, int* __restrict__ bc) {
    int i = blockIdx.x * 256 + threadIdx.x;
    int s = (i < U && cnt[i] >= 2) ? 1 : 0;
    unsigned long long m = __ballot(s);
    __shared__ int wc[4];
    int lane = threadIdx.x & 63, w = threadIdx.x >> 6;
    if (lane == 0) wc[w] = __popcll(m);
    __syncthreads();
    if (threadIdx.x == 0) bc[blockIdx.x] = wc[0] + wc[1] + wc[2] + wc[3];
}

__global__ void k_scan_wave(int* __restrict__ d, int n) {   // 1 block, 64 threads
    int l = threadIdx.x;
    int carry = 0;
    for (int base = 0; base < n; base += 64) {
        int v = (base + l < n) ? d[base + l] : 0;
        int s = v;
        #pragma unroll
        for (int o = 1; o < 64; o <<= 1) {
            int q = __shfl_up(s, o);
            if (l >= o) s += q;
        }
        if (base + l < n) d[base + l] = carry + s - v;   // exclusive
        carry += __shfl(s, 63);
    }
}

__global__ void k_write_sel(const int* __restrict__ cnt, int U,
                            const int* __restrict__ boff, int* __restrict__ sel) {
    int i = blockIdx.x * 256 + threadIdx.x;
    int s = (i < U && cnt[i] >= 2) ? 1 : 0;
    unsigned long long m = __ballot(s);
    __shared__ int wc[4];
    int lane = threadIdx.x & 63, w = threadIdx.x >> 6;
    if (lane == 0) wc[w] = __popcll(m);
    __syncthreads();
    int off = boff[blockIdx.x];
    for (int j = 0; j < w; j++) off += wc[j];
    if (s) sel[off + __popcll(m & ((1ull << lane) - 1ull))] = i;
}

// ---------------- cast + transpose weights to bf16 [N][K] -------------------
__global__ void k_prep_w(const float* __restrict__ w1, const float* __restrict__ w2,
                         ushort* __restrict__ w1t, ushort* __restrict__ w2t) {
    int i = blockIdx.x * 256 + threadIdx.x;
    if (i < 512 * 256) {
        int n = i >> 9, k = i & 511;
        w1t[i] = f2b(w1[k * 256 + n]);
    }
    int j = i - 512 * 256;
    if (j >= 0 && j < 256 * 64) {
        int n = j >> 8, k = j & 255;
        w2t[j] = f2b(w2[k * 64 + n]);
    }
}

// ---------------- featurize v4: 1 wave = 2 rows/iter, MFMA mm2, DPP CBAM ----
__global__ __launch_bounds__(64) void k_feat4(
    const float* __restrict__ vf, const int* __restrict__ winner,
    const int* __restrict__ sel,
    const float* __restrict__ up_w1, const float* __restrict__ up_b1,
    const float* __restrict__ up_w2, const float* __restrict__ up_b2,
    const float* __restrict__ ca_w1, const float* __restrict__ ca_w2,
    const float* __restrict__ sa_conv,
    ushort* __restrict__ xsg, int M, int nw)
{
    __shared__ float sfeat[16 * 12];   // [bin16][feat], stride 12 (16B-aligned rows)

    const int l   = threadIdx.x;
    const int lr  = l & 15;            // A-frag row / channel-low
    const int lk8 = (l >> 4) * 8;      // k-slice base
    const int qsel = (l >> 4) & 1;     // own bin-quad within row (0: bins 0-3)
    const int rowh = l >> 5;           // which voxel-row of the pair

    // ---- per-wave weight preloads (iteration-invariant, VGPR-resident) ----
    float w1v[5][8], b1v[8];
    #pragma unroll
    for (int p = 0; p < 5; p++)
        #pragma unroll
        for (int kk = 0; kk < 8; kk++) w1v[p][kk] = up_w1[p * 32 + lk8 + kk];
    #pragma unroll
    for (int kk = 0; kk < 8; kk++) b1v[kk] = up_b1[lk8 + kk];

    short8 bv[4];
    #pragma unroll
    for (int j = 0; j < 4; j++)
        #pragma unroll
        for (int kk = 0; kk < 8; kk++)
            bv[j][kk] = (short)f2b(up_w2[(lk8 + kk) * 64 + 16 * j + lr]);

    float b2v[4];
    #pragma unroll
    for (int j = 0; j < 4; j++) b2v[j] = up_b2[16 * j + lr];

    const int jjb = qsel * 4;          // which half of the 8 CA-hidden units we own
    float caw1v[4][4];
    #pragma unroll
    for (int j = 0; j < 4; j++)
        #pragma unroll
        for (int o = 0; o < 4; o++)
            caw1v[j][o] = ca_w1[(16 * j + lr) * 8 + jjb + o];
    float caw2v[4][8];
    #pragma unroll
    for (int j = 0; j < 4; j++)
        #pragma unroll
        for (int jj = 0; jj < 8; jj++)
            caw2v[j][jj] = ca_w2[jj * 64 + 16 * j + lr];
    float sas[14];
    #pragma unroll
    for (int k = 0; k < 14; k++) sas[k] = sa_conv[k];

    // ---- gather prefetch (sel -> winner -> vf dependent chain) ----
    auto prefetch = [&](int mb, float4& o4, float& o5) {
        int wv = -1;
        if (l < 16) {
            int mm = mb + (l >> 3);
            if (mm < M) wv = winner[sel[mm] * 8 + (l & 7)];
        }
        int wl = __shfl(wv, lr);
        float4 t4 = make_float4(0.f, 0.f, 0.f, 0.f);
        float t5 = 0.f;
        if (wl >= 0) {
            if (l < 16) {
                const float* p = &vf[(size_t)wl * 5];
                t4.x = p[0]; t4.y = p[1]; t4.z = p[2]; t4.w = p[3];
            } else if (l < 32) {
                t5 = vf[(size_t)wl * 5 + 4];
            }
        }
        o4 = t4; o5 = t5;
    };

    const int step = nw * 2;
    int m2 = blockIdx.x * 2;
    float4 pf; float pf5;
    prefetch(m2, pf, pf5);

    for (; m2 < M; m2 += step) {
        // ---- stage feat to LDS ----
        if (l < 16) *(float4*)&sfeat[lr * 12] = pf;
        else if (l < 32) sfeat[(l & 15) * 12 + 4] = pf5;
        __syncthreads();
        const float4 ff = *(const float4*)&sfeat[lr * 12];
        const float f4e = sfeat[lr * 12 + 4];
        prefetch(m2 + step, pf, pf5);    // overlap next gather with compute

        // ---- mm1: h1[bin16=lr][lk8..+7], straight into A-fragment ----
        float h[8];
        #pragma unroll
        for (int kk = 0; kk < 8; kk++) {
            float a = b1v[kk];
            a = fmaf(ff.x, w1v[0][kk], a);
            a = fmaf(ff.y, w1v[1][kk], a);
            a = fmaf(ff.z, w1v[2][kk], a);
            a = fmaf(ff.w, w1v[3][kk], a);
            a = fmaf(f4e,  w1v[4][kk], a);
            h[kk] = fmaxf(a, 0.0f);
        }
        short8 af;
        #pragma unroll
        for (int kk = 0; kk < 8; kk++) af[kk] = (short)f2b(h[kk]);

        // ---- mm2 via MFMA: (16 bin-rows x 32) @ (32 x 64ch) ----
        const f32x4 z = {0.f, 0.f, 0.f, 0.f};
        float x[4][4];
        #pragma unroll
        for (int j = 0; j < 4; j++) {
            f32x4 a = __builtin_amdgcn_mfma_f32_16x16x32_bf16(af, bv[j], z, 0, 0, 0);
            #pragma unroll
            for (int q = 0; q < 4; q++) x[j][q] = a[q] + b2v[j];
        }
        // lane view: x[j][q] = x[row=rowh][bin = qsel*4+q][ch = 16j+lr]

        // ---- channel attention ----
        float cm[4], cx[4];
        #pragma unroll
        for (int j = 0; j < 4; j++) {
            float s = (x[j][0] + x[j][1]) + (x[j][2] + x[j][3]);
            float mx = fmaxf(fmaxf(x[j][0], x[j][1]), fmaxf(x[j][2], x[j][3]));
            cm[j] = (s + swzf16(s)) * 0.125f;          // mean over 8 bins
            cx[j] = fmaxf(mx, swzf16(mx));             // max over 8 bins
        }
        // 64->8 MLP: each lane does its 4 channels x its 4 hidden units
        float pm[4], px[4];
        #pragma unroll
        for (int o = 0; o < 4; o++) {
            float a = 0.f, b = 0.f;
            #pragma unroll
            for (int j = 0; j < 4; j++) {
                a = fmaf(cm[j], caw1v[j][o], a);
                b = fmaf(cx[j], caw1v[j][o], b);
            }
            pm[o] = a; px[o] = b;
        }
        float hso[4], hsx[4];
        #pragma unroll
        for (int o = 0; o < 4; o++) {
            float a = rsum16(pm[o]);
            float b = rsum16(px[o]);
            hso[o] = fmaxf(a, 0.f) + fmaxf(b, 0.f);    // relu(mean-br)+relu(max-br)
        }
        #pragma unroll
        for (int o = 0; o < 4; o++) hsx[o] = swzf16(hso[o]);
        float hs[8];
        #pragma unroll
        for (int jj = 0; jj < 8; jj++)
            hs[jj] = ((jj >> 2) == qsel) ? hso[jj & 3] : hsx[jj & 3];
        // 8->64 + sigmoid + gate
        #pragma unroll
        for (int j = 0; j < 4; j++) {
            float a = 0.f;
            #pragma unroll
            for (int jj = 0; jj < 8; jj++) a = fmaf(hs[jj], caw2v[j][jj], a);
            float cv = sigm(a);
            x[j][0] *= cv; x[j][1] *= cv; x[j][2] *= cv; x[j][3] *= cv;
        }

        // ---- spatial attention ----
        float sq[4], mq[4];
        #pragma unroll
        for (int q = 0; q < 4; q++) {
            float s = (x[0][q] + x[1][q]) + (x[2][q] + x[3][q]);
            float mx = fmaxf(fmaxf(x[0][q], x[1][q]), fmaxf(x[2][q], x[3][q]));
            sq[q] = rsum16(s);                          // full 64-ch sum for own bins
            mq[q] = rmax16(mx);
        }
        float sq2[4], mq2[4];
        #pragma unroll
        for (int q = 0; q < 4; q++) { sq2[q] = swzf16(sq[q]); mq2[q] = swzf16(mq[q]); }
        float am[8], ax[8];
        #pragma unroll
        for (int b = 0; b < 8; b++) {
            int q = b & 3;
            bool own = ((b >> 2) == qsel);
            am[b] = (own ? sq[q] : sq2[q]) * (1.0f / 64.0f);
            ax[b] = own ? mq[q] : mq2[q];
        }
        float sg[8];
        #pragma unroll
        for (int b = 0; b < 8; b++) {
            float a = 0.f;
            #pragma unroll
            for (int k = 0; k < 7; k++) {
                const int p = b + k - 3;
                if (p >= 0 && p < 8) {
                    a = fmaf(am[p], sas[k], a);
                    a = fmaf(ax[p], sas[7 + k], a);
                }
            }
            sg[b] = sigm(a);
        }
        #pragma unroll
        for (int q = 0; q < 4; q++) {
            float g = qsel ? sg[4 + q] : sg[q];
            x[0][q] *= g; x[1][q] *= g; x[2][q] *= g; x[3][q] *= g;
        }

        // ---- pack bf16, exchange quads, store 16B per channel ----
        unsigned u0[4], u1[4];
        #pragma unroll
        for (int j = 0; j < 4; j++) {
            u0[j] = (unsigned)f2b(x[j][0]) | ((unsigned)f2b(x[j][1]) << 16);
            u1[j] = (unsigned)f2b(x[j][2]) | ((unsigned)f2b(x[j][3]) << 16);
        }
        unsigned o0[4], o1[4];
        #pragma unroll
        for (int j = 0; j < 4; j++) { o0[j] = swzu16(u0[j]); o1[j] = swzu16(u1[j]); }
        if (qsel == 0 && (m2 + rowh) < M) {
            size_t base = (size_t)(m2 + rowh) * 512;
            #pragma unroll
            for (int j = 0; j < 4; j++) {
                uint4 W = make_uint4(u0[j], u1[j], o0[j], o1[j]);  // bins 0..7
                *(uint4*)&xsg[base + (16 * j + lr) * 8] = W;
            }
        }
        __syncthreads();
    }
}

// ---------------- GEMM1 (gload_lds + swizzle) + fused BN1 column stats ------
__global__ __launch_bounds__(256) void k_gemm1(
    const ushort* __restrict__ A, const ushort* __restrict__ B,
    ushort* __restrict__ C, float* __restrict__ ss, int Mp)
{
    __shared__ ushort As[128 * 64];
    __shared__ ushort Bs[128 * 64];
    int t = threadIdx.x;
    int m0 = (blockIdx.x >> 1) * 128;
    int n0 = (blockIdx.x & 1) * 128;
    int l = t & 63, w = t >> 6;
    int wr = w >> 1, wc = w & 1;
    int lr = l & 15, lg = l >> 4, lk = lg * 8;
    f32x4 acc[4][4];
    #pragma unroll
    for (int i = 0; i < 4; i++)
        #pragma unroll
        for (int j = 0; j < 4; j++) acc[i][j] = (f32x4){0.f, 0.f, 0.f, 0.f};

    for (int kt = 0; kt < 512; kt += 64) {
        __syncthreads();
        #pragma unroll
        for (int q = 0; q < 4; q++) {
            int idx = q * 256 + t;
            int row = idx >> 3, kc = (idx & 7) * 8;
            int skc = kc ^ ((row & 7) << 3);            // inverse-swizzled SOURCE
            GL16(&A[(size_t)(m0 + row) * 512 + kt + skc], &As[idx * 8]);
            GL16(&B[(size_t)(n0 + row) * 512 + kt + skc], &Bs[idx * 8]);
        }
        __syncthreads();
        #pragma unroll
        for (int s = 0; s < 2; s++) {
            short8 av[4], bvv[4];
            #pragma unroll
            for (int i = 0; i < 4; i++) {
                int row = wr * 64 + i * 16 + lr;
                av[i] = *(short8*)&As[row * 64 + ((s * 32 + lk) ^ ((row & 7) << 3))];
            }
            #pragma unroll
            for (int j = 0; j < 4; j++) {
                int row = wc * 64 + j * 16 + lr;
                bvv[j] = *(short8*)&Bs[row * 64 + ((s * 32 + lk) ^ ((row & 7) << 3))];
            }
            #pragma unroll
            for (int i = 0; i < 4; i++)
                #pragma unroll
                for (int j = 0; j < 4; j++)
                    acc[i][j] = __builtin_amdgcn_mfma_f32_16x16x32_bf16(av[i], bvv[j], acc[i][j], 0, 0, 0);
        }
    }
    int orow = m0 + wr * 64 + lg * 4;
    int ocol = n0 + wc * 64 + lr;
    float csum[4], csq[4];
    #pragma unroll
    for (int j = 0; j < 4; j++) { csum[j] = 0.f; csq[j] = 0.f; }
    #pragma unroll
    for (int i = 0; i < 4; i++)
        #pragma unroll
        for (int j = 0; j < 4; j++)
            #pragma unroll
            for (int q = 0; q < 4; q++) {
                float v = acc[i][j][q];
                C[(size_t)(orow + i * 16 + q) * 256 + ocol + j * 16] = f2b(v);
                csum[j] += v; csq[j] += v * v;
            }
    #pragma unroll
    for (int j = 0; j < 4; j++) {
        csum[j] += __shfl_xor(csum[j], 16); csum[j] += __shfl_xor(csum[j], 32);
        csq[j]  += __shfl_xor(csq[j], 16);  csq[j]  += __shfl_xor(csq[j], 32);
    }
    if (l < 16) {
        #pragma unroll
        for (int j = 0; j < 4; j++) {
            atomicAdd(&ss[ocol + j * 16], csum[j]);
            atomicAdd(&ss[256 + ocol + j * 16], csq[j]);
        }
    }
}

__global__ void k_finalize(const float* __restrict__ ss, const float* __restrict__ g,
                           const float* __restrict__ b, int C, float invM,
                           float* __restrict__ scsh) {
    int c = threadIdx.x;
    if (c < C) {
        float mean = ss[c] * invM;
        float var  = ss[C + c] * invM - mean * mean;
        float inv  = rsqrtf(var + 0.001f);
        float sc   = g[c] * inv;
        scsh[c]     = sc;
        scsh[C + c] = b[c] - mean * sc;
    }
}

// ---------- GEMM2: BN1+relu fused in A-staging; BN2 stats fused epilogue ----
__global__ __launch_bounds__(256) void k_gemm2(
    const ushort* __restrict__ A, const ushort* __restrict__ B,
    const float* __restrict__ scsh1,
    float* __restrict__ out, float* __restrict__ ss2, int M)
{
    __shared__ ushort As[128 * 64];
    __shared__ ushort Bs[64 * 64];
    __shared__ float s1[512];
    int t = threadIdx.x;
    for (int i = t; i < 512; i += 256) s1[i] = scsh1[i];
    int m0 = blockIdx.x * 128;
    int l = t & 63, w = t >> 6;
    int wr = w >> 1, wc = w & 1;
    int lr = l & 15, lg = l >> 4, lk = lg * 8;
    f32x4 acc[4][2];
    #pragma unroll
    for (int i = 0; i < 4; i++)
        #pragma unroll
        for (int j = 0; j < 2; j++) acc[i][j] = (f32x4){0.f, 0.f, 0.f, 0.f};

    for (int kt = 0; kt < 256; kt += 64) {
        __syncthreads();
        #pragma unroll
        for (int q = 0; q < 2; q++) {
            int idx = q * 256 + t;
            int row = idx >> 3, kc = (idx & 7) * 8;
            int skc = kc ^ ((row & 7) << 3);
            GL16(&B[(size_t)row * 256 + kt + skc], &Bs[idx * 8]);
        }
        #pragma unroll
        for (int q = 0; q < 4; q++) {
            int idx = q * 256 + t;
            int row = idx >> 3, kc = (idx & 7) * 8;
            uint4 av = *(const uint4*)&A[(size_t)(m0 + row) * 256 + kt + kc];
            ushort* ap = (ushort*)&av;
            uint4 pk;
            unsigned* pkp = (unsigned*)&pk;
            #pragma unroll
            for (int h = 0; h < 4; h++) {
                int k0 = kt + kc + 2 * h;
                float v0 = fmaxf(fmaf(b2f(ap[2*h]),   s1[k0],   s1[256 + k0]),   0.f);
                float v1 = fmaxf(fmaf(b2f(ap[2*h+1]), s1[k0+1], s1[256 + k0+1]), 0.f);
                pkp[h] = (unsigned)f2b(v0) | ((unsigned)f2b(v1) << 16);
            }
            *(uint4*)&As[row * 64 + (kc ^ ((row & 7) << 3))] = pk;
        }
        __syncthreads();
        #pragma unroll
        for (int s = 0; s < 2; s++) {
            short8 av[4], bvv[2];
            #pragma unroll
            for (int i = 0; i < 4; i++) {
                int row = wr * 64 + i * 16 + lr;
                av[i] = *(short8*)&As[row * 64 + ((s * 32 + lk) ^ ((row & 7) << 3))];
            }
            #pragma unroll
            for (int j = 0; j < 2; j++) {
                int row = wc * 32 + j * 16 + lr;
                bvv[j] = *(short8*)&Bs[row * 64 + ((s * 32 + lk) ^ ((row & 7) << 3))];
            }
            #pragma unroll
            for (int i = 0; i < 4; i++)
                #pragma unroll
                for (int j = 0; j < 2; j++)
                    acc[i][j] = __builtin_amdgcn_mfma_f32_16x16x32_bf16(av[i], bvv[j], acc[i][j], 0, 0, 0);
        }
    }
    int orow = m0 + wr * 64 + lg * 4;
    int ocol = wc * 32 + lr;
    float csum[2], csq[2];
    #pragma unroll
    for (int j = 0; j < 2; j++) { csum[j] = 0.f; csq[j] = 0.f; }
    #pragma unroll
    for (int i = 0; i < 4; i++)
        #pragma unroll
        for (int j = 0; j < 2; j++)
            #pragma unroll
            for (int q = 0; q < 4; q++) {
                int rr = orow + i * 16 + q;
                if (rr < M) {
                    float v = acc[i][j][q];
                    out[(size_t)rr * 64 + ocol + j * 16] = v;
                    csum[j] += v; csq[j] += v * v;
                }
            }
    #pragma unroll
    for (int j = 0; j < 2; j++) {
        csum[j] += __shfl_xor(csum[j], 16); csum[j] += __shfl_xor(csum[j], 32);
        csq[j]  += __shfl_xor(csq[j], 16);  csq[j]  += __shfl_xor(csq[j], 32);
    }
    if (l < 16) {
        #pragma unroll
        for (int j = 0; j < 2; j++) {
            atomicAdd(&ss2[ocol + j * 16], csum[j]);
            atomicAdd(&ss2[64 + ocol + j * 16], csq[j]);
        }
    }
}

// ---------------- BN2 apply (in place on d_out, float4) ----------------
__global__ void k_bn2_apply4(float4* __restrict__ out4, const float* __restrict__ scsh2, int n4) {
    int i = blockIdx.x * 256 + threadIdx.x;
    if (i < n4) {
        float4 v = out4[i];
        int c0 = (i & 15) * 4;
        v.x = fmaxf(fmaf(v.x, scsh2[c0 + 0], scsh2[64 + c0 + 0]), 0.f);
        v.y = fmaxf(fmaf(v.y, scsh2[c0 + 1], scsh2[64 + c0 + 1]), 0.f);
        v.z = fmaxf(fmaf(v.z, scsh2[c0 + 2], scsh2[64 + c0 + 2]), 0.f);
        v.w = fmaxf(fmaf(v.w, scsh2[c0 + 3], scsh2[64 + c0 + 3]), 0.f);
        out4[i] = v;
    }
}

extern "C" void kernel_launch(void* const* d_in, const int* in_sizes, int n_in,
                              void* d_out, int out_size, void* d_ws, size_t ws_size,
                              hipStream_t stream) {
    const float* vf     = (const float*)d_in[0];
    const int*   coords = (const int*)d_in[1];
    const int*   inv    = (const int*)d_in[3];
    const int*   cnt    = (const int*)d_in[4];
    const float* up_w1  = (const float*)d_in[5];
    const float* up_b1  = (const float*)d_in[6];
    const float* up_w2  = (const float*)d_in[7];
    const float* up_b2  = (const float*)d_in[8];
    const float* ca_w1  = (const float*)d_in[9];
    const float* ca_w2  = (const float*)d_in[10];
    const float* sa_conv= (const float*)d_in[11];
    const float* bs_w1  = (const float*)d_in[12];
    const float* bn1_g  = (const float*)d_in[13];
    const float* bn1_b  = (const float*)d_in[14];
    const float* bs_w2  = (const float*)d_in[15];
    const float* bn2_g  = (const float*)d_in[16];
    const float* bn2_b  = (const float*)d_in[17];

    int Nv = in_sizes[3];
    int U  = in_sizes[4];
    int M  = out_size / 64;
    int Mp = (M + 127) & ~127;
    float* out = (float*)d_out;

    char* ws = (char*)d_ws;
    auto alloc = [&](size_t bytes) -> char* {
        char* p = ws;
        ws += (bytes + 255) / 256 * 256;
        return p;
    };
    int nb = (U + 255) / 256;
    int*    winner = (int*)alloc((size_t)U * 8 * 4);
    int*    bc     = (int*)alloc((size_t)nb * 4);
    int*    sel    = (int*)alloc((size_t)M * 4);
    float*  ss     = (float*)alloc(640 * 4);     // ss1[512] then ss2[128]
    float*  scsh1  = (float*)alloc(512 * 4);
    float*  scsh2  = (float*)alloc(128 * 4);
    ushort* w1t    = (ushort*)alloc((size_t)512 * 256 * 2);
    ushort* w2t    = (ushort*)alloc((size_t)256 * 64 * 2);
    ushort* xsg    = (ushort*)alloc((size_t)Mp * 512 * 2);
    ushort* y1     = (ushort*)alloc((size_t)Mp * 256 * 2);

    hipMemsetAsync(winner, 0xFF, (size_t)U * 8 * 4, stream);
    hipMemsetAsync(ss, 0, 640 * 4, stream);
    if (Mp > M)
        hipMemsetAsync(xsg + (size_t)M * 512, 0, (size_t)(Mp - M) * 512 * 2, stream);

    k_prep_w<<<(512 * 256 + 256 * 64 + 255) / 256, 256, 0, stream>>>(bs_w1, bs_w2, w1t, w2t);
    k_scatter_winner<<<(Nv + 255) / 256, 256, 0, stream>>>(inv, coords, Nv, winner);
    k_count<<<nb, 256, 0, stream>>>(cnt, U, bc);
    k_scan_wave<<<1, 64, 0, stream>>>(bc, nb);
    k_write_sel<<<nb, 256, 0, stream>>>(cnt, U, bc, sel);

    int nwf = 2048;
    k_feat4<<<nwf, 64, 0, stream>>>(
        vf, winner, sel, up_w1, up_b1, up_w2, up_b2,
        ca_w1, ca_w2, sa_conv, xsg, M, nwf);

    k_gemm1<<<(Mp / 128) * 2, 256, 0, stream>>>(xsg, w1t, y1, ss, Mp);
    k_finalize<<<1, 256, 0, stream>>>(ss, bn1_g, bn1_b, 256, 1.0f / (float)M, scsh1);

    k_gemm2<<<Mp / 128, 256, 0, stream>>>(y1, w2t, scsh1, out, ss + 512, M);
    k_finalize<<<1, 64, 0, stream>>>(ss + 512, bn2_g, bn2_b, 64, 1.0f / (float)M, scsh2);

    int n4 = (M * 64) / 4;
    k_bn2_apply4<<<(n4 + 255) / 256, 256, 0, stream>>>((float4*)out, scsh2, n4);
}

// Round 6
// 386.838 us; speedup vs baseline: 4.4597x; 1.0733x over previous
//
#include <hip/hip_runtime.h>
#include <cmath>

typedef __attribute__((ext_vector_type(8))) short short8;
typedef __attribute__((ext_vector_type(4))) float f32x4;

__device__ __forceinline__ ushort f2b(float x) {
    union { float f; unsigned u; } v; v.f = x;
    unsigned r = v.u + 0x7FFFu + ((v.u >> 16) & 1u);
    return (ushort)(r >> 16);
}
__device__ __forceinline__ float b2f(ushort h) {
    union { unsigned u; float f; } v; v.u = ((unsigned)h) << 16; return v.f;
}
__device__ __forceinline__ float sigm(float x) { return 1.0f / (1.0f + __expf(-x)); }

// ---- DPP helpers: 16-lane reductions on the VALU pipe (0 LDS ops) ----------
template <int C>
__device__ __forceinline__ float dppf(float x) {
    return __builtin_bit_cast(float,
        __builtin_amdgcn_update_dpp(0, __builtin_bit_cast(int, x), C, 0xf, 0xf, true));
}
__device__ __forceinline__ float rsum16(float v) {
    v += dppf<0x140>(v);   // row_mirror
    v += dppf<0x141>(v);   // row_half_mirror
    v += dppf<0x1B>(v);    // quad reverse
    v += dppf<0xB1>(v);    // quad xor1
    return v;
}
__device__ __forceinline__ float rmax16(float v) {
    v = fmaxf(v, dppf<0x140>(v));
    v = fmaxf(v, dppf<0x141>(v));
    v = fmaxf(v, dppf<0x1B>(v));
    v = fmaxf(v, dppf<0xB1>(v));
    return v;
}
__device__ __forceinline__ float swzf16(float x) {   // lane ^ 16
    return __builtin_bit_cast(float,
        __builtin_amdgcn_ds_swizzle(__builtin_bit_cast(int, x), 0x401F));
}
__device__ __forceinline__ unsigned swzu16(unsigned x) {
    return (unsigned)__builtin_amdgcn_ds_swizzle((int)x, 0x401F);
}

// ---- async global->LDS, 16B, linear dest (source carries inverse swizzle) --
#define GL16(g, s) __builtin_amdgcn_global_load_lds( \
    (const __attribute__((address_space(1))) unsigned int*)(g), \
    (__attribute__((address_space(3))) unsigned int*)(s), 16, 0, 0)

// ------- prologue: scatter winner + per-block count + weight prep + ss=0 ----
__global__ __launch_bounds__(256) void k_prologue(
    const int* __restrict__ inv, const int* __restrict__ coords, int Nv,
    const int* __restrict__ cnt, int U, int* __restrict__ bc, int nbc,
    const float* __restrict__ w1, const float* __restrict__ w2,
    ushort* __restrict__ w1t, ushort* __restrict__ w2t,
    float* __restrict__ ss, int* __restrict__ winner)
{
    int i = blockIdx.x * 256 + threadIdx.x;
    // scatter: last-write-wins == max voxel index
    if (i < Nv) {
        int u = inv[i];
        int b = coords[i * 4 + 1];
        atomicMax(&winner[u * 8 + b], i);
    }
    // per-block selected count over cnt (same 256-element tiling as write_sel)
    {
        int s = (i < U && cnt[i] >= 2) ? 1 : 0;
        unsigned long long m = __ballot(s);
        __shared__ int wc[4];
        int lane = threadIdx.x & 63, w = threadIdx.x >> 6;
        if (lane == 0) wc[w] = __popcll(m);
        __syncthreads();
        if (threadIdx.x == 0 && blockIdx.x < nbc)
            bc[blockIdx.x] = wc[0] + wc[1] + wc[2] + wc[3];
    }
    // bf16 transposed weights
    if (i < 512 * 256) {
        int n = i >> 9, k = i & 511;
        w1t[i] = f2b(w1[k * 256 + n]);
    }
    int j = i - 512 * 256;
    if (j >= 0 && j < 256 * 64) {
        int n = j >> 8, k = j & 255;
        w2t[j] = f2b(w2[k * 64 + n]);
    }
    // zero stats accumulators
    if (i < 640) ss[i] = 0.0f;
}

// ------- compaction write: block offset = sum of bc[0..blockIdx) ------------
__global__ __launch_bounds__(256) void k_write_sel(
    const int* __restrict__ cnt, int U,
    const int* __restrict__ bc, int* __restrict__ sel)
{
    int i = blockIdx.x * 256 + threadIdx.x;
    int s = (i < U && cnt[i] >= 2) ? 1 : 0;
    unsigned long long m = __ballot(s);
    __shared__ int wc[4], wsum[4];
    int lane = threadIdx.x & 63, w = threadIdx.x >> 6;
    if (lane == 0) wc[w] = __popcll(m);
    int part = 0;
    for (int b = threadIdx.x; b < blockIdx.x; b += 256) part += bc[b];
    #pragma unroll
    for (int o = 1; o < 64; o <<= 1) part += __shfl_xor(part, o);
    if (lane == 0) wsum[w] = part;
    __syncthreads();
    int off = wsum[0] + wsum[1] + wsum[2] + wsum[3];
    for (int jj = 0; jj < w; jj++) off += wc[jj];
    if (s) sel[off + __popcll(m & ((1ull << lane) - 1ull))] = i;
}

// ---------------- featurize v4: 1 wave = 2 rows/iter, MFMA mm2, DPP CBAM ----
__global__ __launch_bounds__(64) void k_feat4(
    const float* __restrict__ vf, const int* __restrict__ winner,
    const int* __restrict__ sel,
    const float* __restrict__ up_w1, const float* __restrict__ up_b1,
    const float* __restrict__ up_w2, const float* __restrict__ up_b2,
    const float* __restrict__ ca_w1, const float* __restrict__ ca_w2,
    const float* __restrict__ sa_conv,
    ushort* __restrict__ xsg, int M, int Mp, int nw)
{
    __shared__ float sfeat[16 * 12];   // [bin16][feat], stride 12 (16B-aligned rows)

    const int l   = threadIdx.x;
    const int lr  = l & 15;            // A-frag row / channel-low
    const int lk8 = (l >> 4) * 8;      // k-slice base
    const int qsel = (l >> 4) & 1;     // own bin-quad within row (0: bins 0-3)
    const int rowh = l >> 5;           // which voxel-row of the pair

    // ---- per-wave weight preloads (iteration-invariant, VGPR-resident) ----
    float w1v[5][8], b1v[8];
    #pragma unroll
    for (int p = 0; p < 5; p++)
        #pragma unroll
        for (int kk = 0; kk < 8; kk++) w1v[p][kk] = up_w1[p * 32 + lk8 + kk];
    #pragma unroll
    for (int kk = 0; kk < 8; kk++) b1v[kk] = up_b1[lk8 + kk];

    short8 bv[4];
    #pragma unroll
    for (int j = 0; j < 4; j++)
        #pragma unroll
        for (int kk = 0; kk < 8; kk++)
            bv[j][kk] = (short)f2b(up_w2[(lk8 + kk) * 64 + 16 * j + lr]);

    float b2v[4];
    #pragma unroll
    for (int j = 0; j < 4; j++) b2v[j] = up_b2[16 * j + lr];

    const int jjb = qsel * 4;          // which half of the 8 CA-hidden units we own
    float caw1v[4][4];
    #pragma unroll
    for (int j = 0; j < 4; j++)
        #pragma unroll
        for (int o = 0; o < 4; o++)
            caw1v[j][o] = ca_w1[(16 * j + lr) * 8 + jjb + o];
    float caw2v[4][8];
    #pragma unroll
    for (int j = 0; j < 4; j++)
        #pragma unroll
        for (int jj = 0; jj < 8; jj++)
            caw2v[j][jj] = ca_w2[jj * 64 + 16 * j + lr];
    float sas[14];
    #pragma unroll
    for (int k = 0; k < 14; k++) sas[k] = sa_conv[k];

    // ---- gather prefetch (sel -> winner -> vf dependent chain) ----
    auto prefetch = [&](int mb, float4& o4, float& o5) {
        int wv = -1;
        if (l < 16) {
            int mm = mb + (l >> 3);
            if (mm < M) wv = winner[sel[mm] * 8 + (l & 7)];
        }
        int wl = __shfl(wv, lr);
        float4 t4 = make_float4(0.f, 0.f, 0.f, 0.f);
        float t5 = 0.f;
        if (wl >= 0) {
            if (l < 16) {
                const float* p = &vf[(size_t)wl * 5];
                t4.x = p[0]; t4.y = p[1]; t4.z = p[2]; t4.w = p[3];
            } else if (l < 32) {
                t5 = vf[(size_t)wl * 5 + 4];
            }
        }
        o4 = t4; o5 = t5;
    };

    const int step = nw * 2;
    int m2 = blockIdx.x * 2;
    float4 pf; float pf5;
    prefetch(m2, pf, pf5);

    for (; m2 < Mp; m2 += step) {
        // ---- stage feat to LDS ----
        if (l < 16) *(float4*)&sfeat[lr * 12] = pf;
        else if (l < 32) sfeat[(l & 15) * 12 + 4] = pf5;
        __syncthreads();
        const float4 ff = *(const float4*)&sfeat[lr * 12];
        const float f4e = sfeat[lr * 12 + 4];
        prefetch(m2 + step, pf, pf5);    // overlap next gather with compute

        // ---- mm1: h1[bin16=lr][lk8..+7], straight into A-fragment ----
        float h[8];
        #pragma unroll
        for (int kk = 0; kk < 8; kk++) {
            float a = b1v[kk];
            a = fmaf(ff.x, w1v[0][kk], a);
            a = fmaf(ff.y, w1v[1][kk], a);
            a = fmaf(ff.z, w1v[2][kk], a);
            a = fmaf(ff.w, w1v[3][kk], a);
            a = fmaf(f4e,  w1v[4][kk], a);
            h[kk] = fmaxf(a, 0.0f);
        }
        short8 af;
        #pragma unroll
        for (int kk = 0; kk < 8; kk++) af[kk] = (short)f2b(h[kk]);

        // ---- mm2 via MFMA: (16 bin-rows x 32) @ (32 x 64ch) ----
        const f32x4 z = {0.f, 0.f, 0.f, 0.f};
        float x[4][4];
        #pragma unroll
        for (int j = 0; j < 4; j++) {
            f32x4 a = __builtin_amdgcn_mfma_f32_16x16x32_bf16(af, bv[j], z, 0, 0, 0);
            #pragma unroll
            for (int q = 0; q < 4; q++) x[j][q] = a[q] + b2v[j];
        }
        // lane view: x[j][q] = x[row=rowh][bin = qsel*4+q][ch = 16j+lr]

        // ---- channel attention ----
        float cm[4], cx[4];
        #pragma unroll
        for (int j = 0; j < 4; j++) {
            float s = (x[j][0] + x[j][1]) + (x[j][2] + x[j][3]);
            float mx = fmaxf(fmaxf(x[j][0], x[j][1]), fmaxf(x[j][2], x[j][3]));
            cm[j] = (s + swzf16(s)) * 0.125f;          // mean over 8 bins
            cx[j] = fmaxf(mx, swzf16(mx));             // max over 8 bins
        }
        float pm[4], px[4];
        #pragma unroll
        for (int o = 0; o < 4; o++) {
            float a = 0.f, b = 0.f;
            #pragma unroll
            for (int j = 0; j < 4; j++) {
                a = fmaf(cm[j], caw1v[j][o], a);
                b = fmaf(cx[j], caw1v[j][o], b);
            }
            pm[o] = a; px[o] = b;
        }
        float hso[4], hsx[4];
        #pragma unroll
        for (int o = 0; o < 4; o++) {
            float a = rsum16(pm[o]);
            float b = rsum16(px[o]);
            hso[o] = fmaxf(a, 0.f) + fmaxf(b, 0.f);    // relu(mean-br)+relu(max-br)
        }
        #pragma unroll
        for (int o = 0; o < 4; o++) hsx[o] = swzf16(hso[o]);
        float hs[8];
        #pragma unroll
        for (int jj = 0; jj < 8; jj++)
            hs[jj] = ((jj >> 2) == qsel) ? hso[jj & 3] : hsx[jj & 3];
        #pragma unroll
        for (int j = 0; j < 4; j++) {
            float a = 0.f;
            #pragma unroll
            for (int jj = 0; jj < 8; jj++) a = fmaf(hs[jj], caw2v[j][jj], a);
            float cv = sigm(a);
            x[j][0] *= cv; x[j][1] *= cv; x[j][2] *= cv; x[j][3] *= cv;
        }

        // ---- spatial attention ----
        float sq[4], mq[4];
        #pragma unroll
        for (int q = 0; q < 4; q++) {
            float s = (x[0][q] + x[1][q]) + (x[2][q] + x[3][q]);
            float mx = fmaxf(fmaxf(x[0][q], x[1][q]), fmaxf(x[2][q], x[3][q]));
            sq[q] = rsum16(s);
            mq[q] = rmax16(mx);
        }
        float sq2[4], mq2[4];
        #pragma unroll
        for (int q = 0; q < 4; q++) { sq2[q] = swzf16(sq[q]); mq2[q] = swzf16(mq[q]); }
        float am[8], ax[8];
        #pragma unroll
        for (int b = 0; b < 8; b++) {
            int q = b & 3;
            bool own = ((b >> 2) == qsel);
            am[b] = (own ? sq[q] : sq2[q]) * (1.0f / 64.0f);
            ax[b] = own ? mq[q] : mq2[q];
        }
        float sg[8];
        #pragma unroll
        for (int b = 0; b < 8; b++) {
            float a = 0.f;
            #pragma unroll
            for (int k = 0; k < 7; k++) {
                const int p = b + k - 3;
                if (p >= 0 && p < 8) {
                    a = fmaf(am[p], sas[k], a);
                    a = fmaf(ax[p], sas[7 + k], a);
                }
            }
            sg[b] = sigm(a);
        }
        #pragma unroll
        for (int q = 0; q < 4; q++) {
            float g = qsel ? sg[4 + q] : sg[q];
            x[0][q] *= g; x[1][q] *= g; x[2][q] *= g; x[3][q] *= g;
        }

        // ---- pack bf16, exchange quads, store 16B per channel ----
        unsigned u0[4], u1[4];
        #pragma unroll
        for (int j = 0; j < 4; j++) {
            u0[j] = (unsigned)f2b(x[j][0]) | ((unsigned)f2b(x[j][1]) << 16);
            u1[j] = (unsigned)f2b(x[j][2]) | ((unsigned)f2b(x[j][3]) << 16);
        }
        unsigned o0[4], o1[4];
        #pragma unroll
        for (int j = 0; j < 4; j++) { o0[j] = swzu16(u0[j]); o1[j] = swzu16(u1[j]); }
        int mrow = m2 + rowh;
        if (qsel == 0 && mrow < Mp) {
            size_t base = (size_t)mrow * 512;
            if (mrow < M) {
                #pragma unroll
                for (int j = 0; j < 4; j++) {
                    uint4 W = make_uint4(u0[j], u1[j], o0[j], o1[j]);  // bins 0..7
                    *(uint4*)&xsg[base + (16 * j + lr) * 8] = W;
                }
            } else {
                const uint4 Z = make_uint4(0u, 0u, 0u, 0u);            // pad rows = 0
                #pragma unroll
                for (int j = 0; j < 4; j++)
                    *(uint4*)&xsg[base + (16 * j + lr) * 8] = Z;
            }
        }
        __syncthreads();
    }
}

// ---------------- GEMM1 (gload_lds + swizzle) + fused BN1 column stats ------
__global__ __launch_bounds__(256) void k_gemm1(
    const ushort* __restrict__ A, const ushort* __restrict__ B,
    ushort* __restrict__ C, float* __restrict__ ss, int Mp)
{
    __shared__ ushort As[128 * 64];
    __shared__ ushort Bs[128 * 64];
    int t = threadIdx.x;
    int m0 = (blockIdx.x >> 1) * 128;
    int n0 = (blockIdx.x & 1) * 128;
    int l = t & 63, w = t >> 6;
    int wr = w >> 1, wc = w & 1;
    int lr = l & 15, lg = l >> 4, lk = lg * 8;
    f32x4 acc[4][4];
    #pragma unroll
    for (int i = 0; i < 4; i++)
        #pragma unroll
        for (int j = 0; j < 4; j++) acc[i][j] = (f32x4){0.f, 0.f, 0.f, 0.f};

    for (int kt = 0; kt < 512; kt += 64) {
        __syncthreads();
        #pragma unroll
        for (int q = 0; q < 4; q++) {
            int idx = q * 256 + t;
            int row = idx >> 3, kc = (idx & 7) * 8;
            int skc = kc ^ ((row & 7) << 3);            // inverse-swizzled SOURCE
            GL16(&A[(size_t)(m0 + row) * 512 + kt + skc], &As[idx * 8]);
            GL16(&B[(size_t)(n0 + row) * 512 + kt + skc], &Bs[idx * 8]);
        }
        __syncthreads();
        #pragma unroll
        for (int s = 0; s < 2; s++) {
            short8 av[4], bvv[4];
            #pragma unroll
            for (int i = 0; i < 4; i++) {
                int row = wr * 64 + i * 16 + lr;
                av[i] = *(short8*)&As[row * 64 + ((s * 32 + lk) ^ ((row & 7) << 3))];
            }
            #pragma unroll
            for (int j = 0; j < 4; j++) {
                int row = wc * 64 + j * 16 + lr;
                bvv[j] = *(short8*)&Bs[row * 64 + ((s * 32 + lk) ^ ((row & 7) << 3))];
            }
            #pragma unroll
            for (int i = 0; i < 4; i++)
                #pragma unroll
                for (int j = 0; j < 4; j++)
                    acc[i][j] = __builtin_amdgcn_mfma_f32_16x16x32_bf16(av[i], bvv[j], acc[i][j], 0, 0, 0);
        }
    }
    int orow = m0 + wr * 64 + lg * 4;
    int ocol = n0 + wc * 64 + lr;
    float csum[4], csq[4];
    #pragma unroll
    for (int j = 0; j < 4; j++) { csum[j] = 0.f; csq[j] = 0.f; }
    #pragma unroll
    for (int i = 0; i < 4; i++)
        #pragma unroll
        for (int j = 0; j < 4; j++)
            #pragma unroll
            for (int q = 0; q < 4; q++) {
                float v = acc[i][j][q];
                C[(size_t)(orow + i * 16 + q) * 256 + ocol + j * 16] = f2b(v);
                csum[j] += v; csq[j] += v * v;
            }
    #pragma unroll
    for (int j = 0; j < 4; j++) {
        csum[j] += __shfl_xor(csum[j], 16); csum[j] += __shfl_xor(csum[j], 32);
        csq[j]  += __shfl_xor(csq[j], 16);  csq[j]  += __shfl_xor(csq[j], 32);
    }
    if (l < 16) {
        #pragma unroll
        for (int j = 0; j < 4; j++) {
            atomicAdd(&ss[ocol + j * 16], csum[j]);
            atomicAdd(&ss[256 + ocol + j * 16], csq[j]);
        }
    }
}

// ---------- GEMM2: inline BN1 finalize + BN1+relu A-staging + BN2 stats -----
__global__ __launch_bounds__(256) void k_gemm2(
    const ushort* __restrict__ A, const ushort* __restrict__ B,
    const float* __restrict__ ss, const float* __restrict__ bn1_g,
    const float* __restrict__ bn1_b, float invM,
    float* __restrict__ out, float* __restrict__ ss2, int M)
{
    __shared__ ushort As[128 * 64];
    __shared__ ushort Bs[64 * 64];
    __shared__ float s1[512];
    int t = threadIdx.x;
    {   // BN1 finalize, per-block (replaces separate k_finalize launch)
        float mean = ss[t] * invM;
        float var  = ss[256 + t] * invM - mean * mean;
        float sc   = bn1_g[t] * rsqrtf(var + 0.001f);
        s1[t]       = sc;
        s1[256 + t] = bn1_b[t] - mean * sc;
    }
    int m0 = blockIdx.x * 128;
    int l = t & 63, w = t >> 6;
    int wr = w >> 1, wc = w & 1;
    int lr = l & 15, lg = l >> 4, lk = lg * 8;
    f32x4 acc[4][2];
    #pragma unroll
    for (int i = 0; i < 4; i++)
        #pragma unroll
        for (int j = 0; j < 2; j++) acc[i][j] = (f32x4){0.f, 0.f, 0.f, 0.f};

    for (int kt = 0; kt < 256; kt += 64) {
        __syncthreads();
        #pragma unroll
        for (int q = 0; q < 2; q++) {
            int idx = q * 256 + t;
            int row = idx >> 3, kc = (idx & 7) * 8;
            int skc = kc ^ ((row & 7) << 3);
            GL16(&B[(size_t)row * 256 + kt + skc], &Bs[idx * 8]);
        }
        #pragma unroll
        for (int q = 0; q < 4; q++) {
            int idx = q * 256 + t;
            int row = idx >> 3, kc = (idx & 7) * 8;
            uint4 av = *(const uint4*)&A[(size_t)(m0 + row) * 256 + kt + kc];
            ushort* ap = (ushort*)&av;
            uint4 pk;
            unsigned* pkp = (unsigned*)&pk;
            #pragma unroll
            for (int h = 0; h < 4; h++) {
                int k0 = kt + kc + 2 * h;
                float v0 = fmaxf(fmaf(b2f(ap[2*h]),   s1[k0],   s1[256 + k0]),   0.f);
                float v1 = fmaxf(fmaf(b2f(ap[2*h+1]), s1[k0+1], s1[256 + k0+1]), 0.f);
                pkp[h] = (unsigned)f2b(v0) | ((unsigned)f2b(v1) << 16);
            }
            *(uint4*)&As[row * 64 + (kc ^ ((row & 7) << 3))] = pk;
        }
        __syncthreads();
        #pragma unroll
        for (int s = 0; s < 2; s++) {
            short8 av[4], bvv[2];
            #pragma unroll
            for (int i = 0; i < 4; i++) {
                int row = wr * 64 + i * 16 + lr;
                av[i] = *(short8*)&As[row * 64 + ((s * 32 + lk) ^ ((row & 7) << 3))];
            }
            #pragma unroll
            for (int j = 0; j < 2; j++) {
                int row = wc * 32 + j * 16 + lr;
                bvv[j] = *(short8*)&Bs[row * 64 + ((s * 32 + lk) ^ ((row & 7) << 3))];
            }
            #pragma unroll
            for (int i = 0; i < 4; i++)
                #pragma unroll
                for (int j = 0; j < 2; j++)
                    acc[i][j] = __builtin_amdgcn_mfma_f32_16x16x32_bf16(av[i], bvv[j], acc[i][j], 0, 0, 0);
        }
    }
    int orow = m0 + wr * 64 + lg * 4;
    int ocol = wc * 32 + lr;
    float csum[2], csq[2];
    #pragma unroll
    for (int j = 0; j < 2; j++) { csum[j] = 0.f; csq[j] = 0.f; }
    #pragma unroll
    for (int i = 0; i < 4; i++)
        #pragma unroll
        for (int j = 0; j < 2; j++)
            #pragma unroll
            for (int q = 0; q < 4; q++) {
                int rr = orow + i * 16 + q;
                if (rr < M) {
                    float v = acc[i][j][q];
                    out[(size_t)rr * 64 + ocol + j * 16] = v;
                    csum[j] += v; csq[j] += v * v;
                }
            }
    #pragma unroll
    for (int j = 0; j < 2; j++) {
        csum[j] += __shfl_xor(csum[j], 16); csum[j] += __shfl_xor(csum[j], 32);
        csq[j]  += __shfl_xor(csq[j], 16);  csq[j]  += __shfl_xor(csq[j], 32);
    }
    if (l < 16) {
        #pragma unroll
        for (int j = 0; j < 2; j++) {
            atomicAdd(&ss2[ocol + j * 16], csum[j]);
            atomicAdd(&ss2[64 + ocol + j * 16], csq[j]);
        }
    }
}

// ---------------- BN2 finalize (inline) + apply, float4 in place ------------
__global__ __launch_bounds__(256) void k_bn2_apply4(
    float4* __restrict__ out4, const float* __restrict__ ss2,
    const float* __restrict__ bn2_g, const float* __restrict__ bn2_b,
    float invM, int n4)
{
    __shared__ float s2[128];
    if (threadIdx.x < 64) {
        int c = threadIdx.x;
        float mean = ss2[c] * invM;
        float var  = ss2[64 + c] * invM - mean * mean;
        float sc   = bn2_g[c] * rsqrtf(var + 0.001f);
        s2[c]      = sc;
        s2[64 + c] = bn2_b[c] - mean * sc;
    }
    __syncthreads();
    int i = blockIdx.x * 256 + threadIdx.x;
    if (i < n4) {
        float4 v = out4[i];
        int c0 = (i & 15) * 4;
        v.x = fmaxf(fmaf(v.x, s2[c0 + 0], s2[64 + c0 + 0]), 0.f);
        v.y = fmaxf(fmaf(v.y, s2[c0 + 1], s2[64 + c0 + 1]), 0.f);
        v.z = fmaxf(fmaf(v.z, s2[c0 + 2], s2[64 + c0 + 2]), 0.f);
        v.w = fmaxf(fmaf(v.w, s2[c0 + 3], s2[64 + c0 + 3]), 0.f);
        out4[i] = v;
    }
}

extern "C" void kernel_launch(void* const* d_in, const int* in_sizes, int n_in,
                              void* d_out, int out_size, void* d_ws, size_t ws_size,
                              hipStream_t stream) {
    const float* vf     = (const float*)d_in[0];
    const int*   coords = (const int*)d_in[1];
    const int*   inv    = (const int*)d_in[3];
    const int*   cnt    = (const int*)d_in[4];
    const float* up_w1  = (const float*)d_in[5];
    const float* up_b1  = (const float*)d_in[6];
    const float* up_w2  = (const float*)d_in[7];
    const float* up_b2  = (const float*)d_in[8];
    const float* ca_w1  = (const float*)d_in[9];
    const float* ca_w2  = (const float*)d_in[10];
    const float* sa_conv= (const float*)d_in[11];
    const float* bs_w1  = (const float*)d_in[12];
    const float* bn1_g  = (const float*)d_in[13];
    const float* bn1_b  = (const float*)d_in[14];
    const float* bs_w2  = (const float*)d_in[15];
    const float* bn2_g  = (const float*)d_in[16];
    const float* bn2_b  = (const float*)d_in[17];

    int Nv = in_sizes[3];
    int U  = in_sizes[4];
    int M  = out_size / 64;
    int Mp = (M + 127) & ~127;
    float* out = (float*)d_out;

    char* ws = (char*)d_ws;
    auto alloc = [&](size_t bytes) -> char* {
        char* p = ws;
        ws += (bytes + 255) / 256 * 256;
        return p;
    };
    int nb = (U + 255) / 256;
    int*    winner = (int*)alloc((size_t)U * 8 * 4);
    int*    bc     = (int*)alloc((size_t)nb * 4);
    int*    sel    = (int*)alloc((size_t)M * 4);
    float*  ss     = (float*)alloc(640 * 4);     // ss1[512] then ss2[128]
    ushort* w1t    = (ushort*)alloc((size_t)512 * 256 * 2);
    ushort* w2t    = (ushort*)alloc((size_t)256 * 64 * 2);
    ushort* xsg    = (ushort*)alloc((size_t)Mp * 512 * 2);
    ushort* y1     = (ushort*)alloc((size_t)Mp * 256 * 2);

    hipMemsetAsync(winner, 0xFF, (size_t)U * 8 * 4, stream);   // -1 (needed: atomicMax floor)

    int npro = (Nv + 255) / 256;   // covers Nv > 512*256+64*256 and U
    k_prologue<<<npro, 256, 0, stream>>>(inv, coords, Nv, cnt, U, bc, nb,
                                         bs_w1, bs_w2, w1t, w2t, ss, winner);
    k_write_sel<<<nb, 256, 0, stream>>>(cnt, U, bc, sel);

    int nwf = 8192;
    k_feat4<<<nwf, 64, 0, stream>>>(
        vf, winner, sel, up_w1, up_b1, up_w2, up_b2,
        ca_w1, ca_w2, sa_conv, xsg, M, Mp, nwf);

    k_gemm1<<<(Mp / 128) * 2, 256, 0, stream>>>(xsg, w1t, y1, ss, Mp);

    k_gemm2<<<Mp / 128, 256, 0, stream>>>(y1, w2t, ss, bn1_g, bn1_b,
                                          1.0f / (float)M, out, ss + 512, M);

    int n4 = (M * 64) / 4;
    k_bn2_apply4<<<(n4 + 255) / 256, 256, 0, stream>>>(
        (float4*)out, ss + 512, bn2_g, bn2_b, 1.0f / (float)M, n4);
}

// Round 7
// 384.524 us; speedup vs baseline: 4.4865x; 1.0060x over previous
//
#include <hip/hip_runtime.h>
#include <cmath>

typedef __attribute__((ext_vector_type(8))) short short8;
typedef __attribute__((ext_vector_type(4))) float f32x4;

__device__ __forceinline__ ushort f2b(float x) {
    union { float f; unsigned u; } v; v.f = x;
    unsigned r = v.u + 0x7FFFu + ((v.u >> 16) & 1u);
    return (ushort)(r >> 16);
}
__device__ __forceinline__ float b2f(ushort h) {
    union { unsigned u; float f; } v; v.u = ((unsigned)h) << 16; return v.f;
}
__device__ __forceinline__ float sigm(float x) { return 1.0f / (1.0f + __expf(-x)); }

// ---- DPP helpers: 16-lane reductions on the VALU pipe (0 LDS ops) ----------
template <int C>
__device__ __forceinline__ float dppf(float x) {
    return __builtin_bit_cast(float,
        __builtin_amdgcn_update_dpp(0, __builtin_bit_cast(int, x), C, 0xf, 0xf, true));
}
__device__ __forceinline__ float rsum16(float v) {
    v += dppf<0x140>(v);   // row_mirror
    v += dppf<0x141>(v);   // row_half_mirror
    v += dppf<0x1B>(v);    // quad reverse
    v += dppf<0xB1>(v);    // quad xor1
    return v;
}
__device__ __forceinline__ float rmax16(float v) {
    v = fmaxf(v, dppf<0x140>(v));
    v = fmaxf(v, dppf<0x141>(v));
    v = fmaxf(v, dppf<0x1B>(v));
    v = fmaxf(v, dppf<0xB1>(v));
    return v;
}
__device__ __forceinline__ float swzf16(float x) {   // lane ^ 16
    return __builtin_bit_cast(float,
        __builtin_amdgcn_ds_swizzle(__builtin_bit_cast(int, x), 0x401F));
}
__device__ __forceinline__ unsigned swzu16(unsigned x) {
    return (unsigned)__builtin_amdgcn_ds_swizzle((int)x, 0x401F);
}

// ---- async global->LDS, 16B, linear dest (source carries inverse swizzle) --
#define GL16(g, s) __builtin_amdgcn_global_load_lds( \
    (const __attribute__((address_space(1))) unsigned int*)(g), \
    (__attribute__((address_space(3))) unsigned int*)(s), 16, 0, 0)

// ------- prologue: scatter winner + per-block count + weight prep + ss=0 ----
__global__ __launch_bounds__(256) void k_prologue(
    const int* __restrict__ inv, const int* __restrict__ coords, int Nv,
    const int* __restrict__ cnt, int U, int* __restrict__ bc, int nbc,
    const float* __restrict__ w1, const float* __restrict__ w2,
    ushort* __restrict__ w1t, ushort* __restrict__ w2t,
    float* __restrict__ ss, int* __restrict__ winner)
{
    int i = blockIdx.x * 256 + threadIdx.x;
    if (i < Nv) {
        int u = inv[i];
        int b = coords[i * 4 + 1];
        atomicMax(&winner[u * 8 + b], i);
    }
    {
        int s = (i < U && cnt[i] >= 2) ? 1 : 0;
        unsigned long long m = __ballot(s);
        __shared__ int wc[4];
        int lane = threadIdx.x & 63, w = threadIdx.x >> 6;
        if (lane == 0) wc[w] = __popcll(m);
        __syncthreads();
        if (threadIdx.x == 0 && blockIdx.x < nbc)
            bc[blockIdx.x] = wc[0] + wc[1] + wc[2] + wc[3];
    }
    if (i < 512 * 256) {
        int n = i >> 9, k = i & 511;
        w1t[i] = f2b(w1[k * 256 + n]);
    }
    int j = i - 512 * 256;
    if (j >= 0 && j < 256 * 64) {
        int n = j >> 8, k = j & 255;
        w2t[j] = f2b(w2[k * 64 + n]);
    }
    if (i < 640) ss[i] = 0.0f;
}

// ------- compaction write: block offset = sum of bc[0..blockIdx) ------------
__global__ __launch_bounds__(256) void k_write_sel(
    const int* __restrict__ cnt, int U,
    const int* __restrict__ bc, int* __restrict__ sel)
{
    int i = blockIdx.x * 256 + threadIdx.x;
    int s = (i < U && cnt[i] >= 2) ? 1 : 0;
    unsigned long long m = __ballot(s);
    __shared__ int wc[4], wsum[4];
    int lane = threadIdx.x & 63, w = threadIdx.x >> 6;
    if (lane == 0) wc[w] = __popcll(m);
    int part = 0;
    for (int b = threadIdx.x; b < blockIdx.x; b += 256) part += bc[b];
    #pragma unroll
    for (int o = 1; o < 64; o <<= 1) part += __shfl_xor(part, o);
    if (lane == 0) wsum[w] = part;
    __syncthreads();
    int off = wsum[0] + wsum[1] + wsum[2] + wsum[3];
    for (int jj = 0; jj < w; jj++) off += wc[jj];
    if (s) sel[off + __popcll(m & ((1ull << lane) - 1ull))] = i;
}

// ------ featurize v5: 4 independent waves/WG, no LDS, no barriers -----------
__global__ __launch_bounds__(256) void k_feat5(
    const float* __restrict__ vf, const int* __restrict__ winner,
    const int* __restrict__ sel,
    const float* __restrict__ up_w1, const float* __restrict__ up_b1,
    const float* __restrict__ up_w2, const float* __restrict__ up_b2,
    const float* __restrict__ ca_w1, const float* __restrict__ ca_w2,
    const float* __restrict__ sa_conv,
    ushort* __restrict__ xsg, int M, int Mp, int nwave)
{
    const int l    = threadIdx.x & 63;
    const int lr   = l & 15;           // A-frag row / channel-low
    const int lk8  = (l >> 4) * 8;     // k-slice base
    const int qsel = (l >> 4) & 1;     // own bin-quad within row
    const int rowh = l >> 5;           // which voxel-row of the pair
    const int gw   = blockIdx.x * 4 + (threadIdx.x >> 6);

    // ---- per-wave weight preloads (iteration-invariant, VGPR-resident) ----
    float w1v[5][8], b1v[8];
    #pragma unroll
    for (int p = 0; p < 5; p++)
        #pragma unroll
        for (int kk = 0; kk < 8; kk++) w1v[p][kk] = up_w1[p * 32 + lk8 + kk];
    #pragma unroll
    for (int kk = 0; kk < 8; kk++) b1v[kk] = up_b1[lk8 + kk];

    short8 bv[4];
    #pragma unroll
    for (int j = 0; j < 4; j++)
        #pragma unroll
        for (int kk = 0; kk < 8; kk++)
            bv[j][kk] = (short)f2b(up_w2[(lk8 + kk) * 64 + 16 * j + lr]);

    float b2v[4];
    #pragma unroll
    for (int j = 0; j < 4; j++) b2v[j] = up_b2[16 * j + lr];

    const int jjb = qsel * 4;
    float caw1v[4][4];
    #pragma unroll
    for (int j = 0; j < 4; j++)
        #pragma unroll
        for (int o = 0; o < 4; o++)
            caw1v[j][o] = ca_w1[(16 * j + lr) * 8 + jjb + o];
    float caw2v[4][8];
    #pragma unroll
    for (int j = 0; j < 4; j++)
        #pragma unroll
        for (int jj = 0; jj < 8; jj++)
            caw2v[j][jj] = ca_w2[jj * 64 + 16 * j + lr];
    float sas[14];
    #pragma unroll
    for (int k = 0; k < 14; k++) sas[k] = sa_conv[k];

    // ---- gather prefetch: lanes 0-15 load float4, lanes 16-31 the 5th ------
    auto prefetch = [&](int mb, float4& o4, float& o5) {
        int wv = -1;
        if (l < 16) {
            int mm = mb + (l >> 3);
            if (mm < M) wv = winner[sel[mm] * 8 + (l & 7)];
        }
        int wl = __shfl(wv, lr);
        float4 t4 = make_float4(0.f, 0.f, 0.f, 0.f);
        float t5 = 0.f;
        if (wl >= 0) {
            if (l < 16) {
                const float* p = &vf[(size_t)wl * 5];
                t4.x = p[0]; t4.y = p[1]; t4.z = p[2]; t4.w = p[3];
            } else if (l < 32) {
                t5 = vf[(size_t)wl * 5 + 4];
            }
        }
        o4 = t4; o5 = t5;
    };

    const int step = nwave * 2;
    int m2 = gw * 2;
    float4 pf; float pf5;
    prefetch(m2, pf, pf5);

    for (; m2 < Mp; m2 += step) {
        // ---- broadcast feat via shuffles (replaces LDS round-trip) ----
        float4 ff;
        ff.x = __shfl(pf.x, lr); ff.y = __shfl(pf.y, lr);
        ff.z = __shfl(pf.z, lr); ff.w = __shfl(pf.w, lr);
        float f4e = __shfl(pf5, 16 + lr);
        prefetch(m2 + step, pf, pf5);    // issue next gather under compute

        // ---- mm1: h1[bin16=lr][lk8..+7], straight into A-fragment ----
        float h[8];
        #pragma unroll
        for (int kk = 0; kk < 8; kk++) {
            float a = b1v[kk];
            a = fmaf(ff.x, w1v[0][kk], a);
            a = fmaf(ff.y, w1v[1][kk], a);
            a = fmaf(ff.z, w1v[2][kk], a);
            a = fmaf(ff.w, w1v[3][kk], a);
            a = fmaf(f4e,  w1v[4][kk], a);
            h[kk] = fmaxf(a, 0.0f);
        }
        short8 af;
        #pragma unroll
        for (int kk = 0; kk < 8; kk++) af[kk] = (short)f2b(h[kk]);

        // ---- mm2 via MFMA: (16 bin-rows x 32) @ (32 x 64ch) ----
        const f32x4 z = {0.f, 0.f, 0.f, 0.f};
        float x[4][4];
        #pragma unroll
        for (int j = 0; j < 4; j++) {
            f32x4 a = __builtin_amdgcn_mfma_f32_16x16x32_bf16(af, bv[j], z, 0, 0, 0);
            #pragma unroll
            for (int q = 0; q < 4; q++) x[j][q] = a[q] + b2v[j];
        }
        // lane view: x[j][q] = x[row=rowh][bin = qsel*4+q][ch = 16j+lr]

        // ---- channel attention ----
        float cm[4], cx[4];
        #pragma unroll
        for (int j = 0; j < 4; j++) {
            float s = (x[j][0] + x[j][1]) + (x[j][2] + x[j][3]);
            float mx = fmaxf(fmaxf(x[j][0], x[j][1]), fmaxf(x[j][2], x[j][3]));
            cm[j] = (s + swzf16(s)) * 0.125f;
            cx[j] = fmaxf(mx, swzf16(mx));
        }
        float pm[4], px[4];
        #pragma unroll
        for (int o = 0; o < 4; o++) {
            float a = 0.f, b = 0.f;
            #pragma unroll
            for (int j = 0; j < 4; j++) {
                a = fmaf(cm[j], caw1v[j][o], a);
                b = fmaf(cx[j], caw1v[j][o], b);
            }
            pm[o] = a; px[o] = b;
        }
        float hso[4], hsx[4];
        #pragma unroll
        for (int o = 0; o < 4; o++) {
            float a = rsum16(pm[o]);
            float b = rsum16(px[o]);
            hso[o] = fmaxf(a, 0.f) + fmaxf(b, 0.f);
        }
        #pragma unroll
        for (int o = 0; o < 4; o++) hsx[o] = swzf16(hso[o]);
        float hs[8];
        #pragma unroll
        for (int jj = 0; jj < 8; jj++)
            hs[jj] = ((jj >> 2) == qsel) ? hso[jj & 3] : hsx[jj & 3];
        #pragma unroll
        for (int j = 0; j < 4; j++) {
            float a = 0.f;
            #pragma unroll
            for (int jj = 0; jj < 8; jj++) a = fmaf(hs[jj], caw2v[j][jj], a);
            float cv = sigm(a);
            x[j][0] *= cv; x[j][1] *= cv; x[j][2] *= cv; x[j][3] *= cv;
        }

        // ---- spatial attention ----
        float sq[4], mq[4];
        #pragma unroll
        for (int q = 0; q < 4; q++) {
            float s = (x[0][q] + x[1][q]) + (x[2][q] + x[3][q]);
            float mx = fmaxf(fmaxf(x[0][q], x[1][q]), fmaxf(x[2][q], x[3][q]));
            sq[q] = rsum16(s);
            mq[q] = rmax16(mx);
        }
        float sq2[4], mq2[4];
        #pragma unroll
        for (int q = 0; q < 4; q++) { sq2[q] = swzf16(sq[q]); mq2[q] = swzf16(mq[q]); }
        float am[8], ax[8];
        #pragma unroll
        for (int b = 0; b < 8; b++) {
            int q = b & 3;
            bool own = ((b >> 2) == qsel);
            am[b] = (own ? sq[q] : sq2[q]) * (1.0f / 64.0f);
            ax[b] = own ? mq[q] : mq2[q];
        }
        float sg[8];
        #pragma unroll
        for (int b = 0; b < 8; b++) {
            float a = 0.f;
            #pragma unroll
            for (int k = 0; k < 7; k++) {
                const int p = b + k - 3;
                if (p >= 0 && p < 8) {
                    a = fmaf(am[p], sas[k], a);
                    a = fmaf(ax[p], sas[7 + k], a);
                }
            }
            sg[b] = sigm(a);
        }
        #pragma unroll
        for (int q = 0; q < 4; q++) {
            float g = qsel ? sg[4 + q] : sg[q];
            x[0][q] *= g; x[1][q] *= g; x[2][q] *= g; x[3][q] *= g;
        }

        // ---- pack bf16, exchange quads, store 16B per channel ----
        unsigned u0[4], u1[4];
        #pragma unroll
        for (int j = 0; j < 4; j++) {
            u0[j] = (unsigned)f2b(x[j][0]) | ((unsigned)f2b(x[j][1]) << 16);
            u1[j] = (unsigned)f2b(x[j][2]) | ((unsigned)f2b(x[j][3]) << 16);
        }
        unsigned o0[4], o1[4];
        #pragma unroll
        for (int j = 0; j < 4; j++) { o0[j] = swzu16(u0[j]); o1[j] = swzu16(u1[j]); }
        int mrow = m2 + rowh;
        if (qsel == 0 && mrow < Mp) {
            size_t base = (size_t)mrow * 512;
            if (mrow < M) {
                #pragma unroll
                for (int j = 0; j < 4; j++) {
                    uint4 W = make_uint4(u0[j], u1[j], o0[j], o1[j]);
                    *(uint4*)&xsg[base + (16 * j + lr) * 8] = W;
                }
            } else {
                const uint4 Z = make_uint4(0u, 0u, 0u, 0u);
                #pragma unroll
                for (int j = 0; j < 4; j++)
                    *(uint4*)&xsg[base + (16 * j + lr) * 8] = Z;
            }
        }
    }
}

// ----- GEMM1: 128x256 tile, 8 waves, A fetched ONCE; fused BN1 stats --------
__global__ __launch_bounds__(512) void k_gemm1(
    const ushort* __restrict__ A, const ushort* __restrict__ B,
    ushort* __restrict__ C, float* __restrict__ ss, int Mp)
{
    __shared__ ushort As[128 * 64];    // 16 KB
    __shared__ ushort Bs[256 * 64];    // 32 KB
    int t = threadIdx.x;
    int m0 = blockIdx.x * 128;
    int l = t & 63, w = t >> 6;
    int wr = w >> 2, wc = w & 3;       // 2 x 4 wave grid, per-wave 64x64
    int lr = l & 15, lg = l >> 4, lk = lg * 8;
    f32x4 acc[4][4];
    #pragma unroll
    for (int i = 0; i < 4; i++)
        #pragma unroll
        for (int j = 0; j < 4; j++) acc[i][j] = (f32x4){0.f, 0.f, 0.f, 0.f};

    for (int kt = 0; kt < 512; kt += 64) {
        __syncthreads();
        #pragma unroll
        for (int q = 0; q < 2; q++) {
            int idx = q * 512 + t;                 // A: 1024 x 16B
            int row = idx >> 3, kc = (idx & 7) * 8;
            int skc = kc ^ ((row & 7) << 3);
            GL16(&A[(size_t)(m0 + row) * 512 + kt + skc], &As[idx * 8]);
        }
        #pragma unroll
        for (int q = 0; q < 4; q++) {
            int idx = q * 512 + t;                 // B: 2048 x 16B
            int row = idx >> 3, kc = (idx & 7) * 8;
            int skc = kc ^ ((row & 7) << 3);
            GL16(&B[(size_t)row * 512 + kt + skc], &Bs[idx * 8]);
        }
        __syncthreads();
        #pragma unroll
        for (int s = 0; s < 2; s++) {
            short8 av[4], bvv[4];
            #pragma unroll
            for (int i = 0; i < 4; i++) {
                int row = wr * 64 + i * 16 + lr;
                av[i] = *(short8*)&As[row * 64 + ((s * 32 + lk) ^ ((row & 7) << 3))];
            }
            #pragma unroll
            for (int j = 0; j < 4; j++) {
                int row = wc * 64 + j * 16 + lr;
                bvv[j] = *(short8*)&Bs[row * 64 + ((s * 32 + lk) ^ ((row & 7) << 3))];
            }
            #pragma unroll
            for (int i = 0; i < 4; i++)
                #pragma unroll
                for (int j = 0; j < 4; j++)
                    acc[i][j] = __builtin_amdgcn_mfma_f32_16x16x32_bf16(av[i], bvv[j], acc[i][j], 0, 0, 0);
        }
    }
    int orow = m0 + wr * 64 + lg * 4;
    int ocol = wc * 64 + lr;
    float csum[4], csq[4];
    #pragma unroll
    for (int j = 0; j < 4; j++) { csum[j] = 0.f; csq[j] = 0.f; }
    #pragma unroll
    for (int i = 0; i < 4; i++)
        #pragma unroll
        for (int j = 0; j < 4; j++)
            #pragma unroll
            for (int q = 0; q < 4; q++) {
                float v = acc[i][j][q];
                C[(size_t)(orow + i * 16 + q) * 256 + ocol + j * 16] = f2b(v);
                csum[j] += v; csq[j] += v * v;
            }
    #pragma unroll
    for (int j = 0; j < 4; j++) {
        csum[j] += __shfl_xor(csum[j], 16); csum[j] += __shfl_xor(csum[j], 32);
        csq[j]  += __shfl_xor(csq[j], 16);  csq[j]  += __shfl_xor(csq[j], 32);
    }
    if (l < 16) {
        #pragma unroll
        for (int j = 0; j < 4; j++) {
            atomicAdd(&ss[ocol + j * 16], csum[j]);
            atomicAdd(&ss[256 + ocol + j * 16], csq[j]);
        }
    }
}

// ---------- GEMM2: inline BN1 finalize + BN1+relu A-staging + BN2 stats -----
__global__ __launch_bounds__(256) void k_gemm2(
    const ushort* __restrict__ A, const ushort* __restrict__ B,
    const float* __restrict__ ss, const float* __restrict__ bn1_g,
    const float* __restrict__ bn1_b, float invM,
    float* __restrict__ out, float* __restrict__ ss2, int M)
{
    __shared__ ushort As[128 * 64];
    __shared__ ushort Bs[64 * 64];
    __shared__ float s1[512];
    int t = threadIdx.x;
    {
        float mean = ss[t] * invM;
        float var  = ss[256 + t] * invM - mean * mean;
        float sc   = bn1_g[t] * rsqrtf(var + 0.001f);
        s1[t]       = sc;
        s1[256 + t] = bn1_b[t] - mean * sc;
    }
    int m0 = blockIdx.x * 128;
    int l = t & 63, w = t >> 6;
    int wr = w >> 1, wc = w & 1;
    int lr = l & 15, lg = l >> 4, lk = lg * 8;
    f32x4 acc[4][2];
    #pragma unroll
    for (int i = 0; i < 4; i++)
        #pragma unroll
        for (int j = 0; j < 2; j++) acc[i][j] = (f32x4){0.f, 0.f, 0.f, 0.f};

    for (int kt = 0; kt < 256; kt += 64) {
        __syncthreads();
        #pragma unroll
        for (int q = 0; q < 2; q++) {
            int idx = q * 256 + t;
            int row = idx >> 3, kc = (idx & 7) * 8;
            int skc = kc ^ ((row & 7) << 3);
            GL16(&B[(size_t)row * 256 + kt + skc], &Bs[idx * 8]);
        }
        #pragma unroll
        for (int q = 0; q < 4; q++) {
            int idx = q * 256 + t;
            int row = idx >> 3, kc = (idx & 7) * 8;
            uint4 av = *(const uint4*)&A[(size_t)(m0 + row) * 256 + kt + kc];
            ushort* ap = (ushort*)&av;
            uint4 pk;
            unsigned* pkp = (unsigned*)&pk;
            #pragma unroll
            for (int h = 0; h < 4; h++) {
                int k0 = kt + kc + 2 * h;
                float v0 = fmaxf(fmaf(b2f(ap[2*h]),   s1[k0],   s1[256 + k0]),   0.f);
                float v1 = fmaxf(fmaf(b2f(ap[2*h+1]), s1[k0+1], s1[256 + k0+1]), 0.f);
                pkp[h] = (unsigned)f2b(v0) | ((unsigned)f2b(v1) << 16);
            }
            *(uint4*)&As[row * 64 + (kc ^ ((row & 7) << 3))] = pk;
        }
        __syncthreads();
        #pragma unroll
        for (int s = 0; s < 2; s++) {
            short8 av[4], bvv[2];
            #pragma unroll
            for (int i = 0; i < 4; i++) {
                int row = wr * 64 + i * 16 + lr;
                av[i] = *(short8*)&As[row * 64 + ((s * 32 + lk) ^ ((row & 7) << 3))];
            }
            #pragma unroll
            for (int j = 0; j < 2; j++) {
                int row = wc * 32 + j * 16 + lr;
                bvv[j] = *(short8*)&Bs[row * 64 + ((s * 32 + lk) ^ ((row & 7) << 3))];
            }
            #pragma unroll
            for (int i = 0; i < 4; i++)
                #pragma unroll
                for (int j = 0; j < 2; j++)
                    acc[i][j] = __builtin_amdgcn_mfma_f32_16x16x32_bf16(av[i], bvv[j], acc[i][j], 0, 0, 0);
        }
    }
    int orow = m0 + wr * 64 + lg * 4;
    int ocol = wc * 32 + lr;
    float csum[2], csq[2];
    #pragma unroll
    for (int j = 0; j < 2; j++) { csum[j] = 0.f; csq[j] = 0.f; }
    #pragma unroll
    for (int i = 0; i < 4; i++)
        #pragma unroll
        for (int j = 0; j < 2; j++)
            #pragma unroll
            for (int q = 0; q < 4; q++) {
                int rr = orow + i * 16 + q;
                if (rr < M) {
                    float v = acc[i][j][q];
                    out[(size_t)rr * 64 + ocol + j * 16] = v;
                    csum[j] += v; csq[j] += v * v;
                }
            }
    #pragma unroll
    for (int j = 0; j < 2; j++) {
        csum[j] += __shfl_xor(csum[j], 16); csum[j] += __shfl_xor(csum[j], 32);
        csq[j]  += __shfl_xor(csq[j], 16);  csq[j]  += __shfl_xor(csq[j], 32);
    }
    if (l < 16) {
        #pragma unroll
        for (int j = 0; j < 2; j++) {
            atomicAdd(&ss2[ocol + j * 16], csum[j]);
            atomicAdd(&ss2[64 + ocol + j * 16], csq[j]);
        }
    }
}

// ---------------- BN2 finalize (inline) + apply, float4 in place ------------
__global__ __launch_bounds__(256) void k_bn2_apply4(
    float4* __restrict__ out4, const float* __restrict__ ss2,
    const float* __restrict__ bn2_g, const float* __restrict__ bn2_b,
    float invM, int n4)
{
    __shared__ float s2[128];
    if (threadIdx.x < 64) {
        int c = threadIdx.x;
        float mean = ss2[c] * invM;
        float var  = ss2[64 + c] * invM - mean * mean;
        float sc   = bn2_g[c] * rsqrtf(var + 0.001f);
        s2[c]      = sc;
        s2[64 + c] = bn2_b[c] - mean * sc;
    }
    __syncthreads();
    int i = blockIdx.x * 256 + threadIdx.x;
    if (i < n4) {
        float4 v = out4[i];
        int c0 = (i & 15) * 4;
        v.x = fmaxf(fmaf(v.x, s2[c0 + 0], s2[64 + c0 + 0]), 0.f);
        v.y = fmaxf(fmaf(v.y, s2[c0 + 1], s2[64 + c0 + 1]), 0.f);
        v.z = fmaxf(fmaf(v.z, s2[c0 + 2], s2[64 + c0 + 2]), 0.f);
        v.w = fmaxf(fmaf(v.w, s2[c0 + 3], s2[64 + c0 + 3]), 0.f);
        out4[i] = v;
    }
}

extern "C" void kernel_launch(void* const* d_in, const int* in_sizes, int n_in,
                              void* d_out, int out_size, void* d_ws, size_t ws_size,
                              hipStream_t stream) {
    const float* vf     = (const float*)d_in[0];
    const int*   coords = (const int*)d_in[1];
    const int*   inv    = (const int*)d_in[3];
    const int*   cnt    = (const int*)d_in[4];
    const float* up_w1  = (const float*)d_in[5];
    const float* up_b1  = (const float*)d_in[6];
    const float* up_w2  = (const float*)d_in[7];
    const float* up_b2  = (const float*)d_in[8];
    const float* ca_w1  = (const float*)d_in[9];
    const float* ca_w2  = (const float*)d_in[10];
    const float* sa_conv= (const float*)d_in[11];
    const float* bs_w1  = (const float*)d_in[12];
    const float* bn1_g  = (const float*)d_in[13];
    const float* bn1_b  = (const float*)d_in[14];
    const float* bs_w2  = (const float*)d_in[15];
    const float* bn2_g  = (const float*)d_in[16];
    const float* bn2_b  = (const float*)d_in[17];

    int Nv = in_sizes[3];
    int U  = in_sizes[4];
    int M  = out_size / 64;
    int Mp = (M + 127) & ~127;
    float* out = (float*)d_out;

    char* ws = (char*)d_ws;
    auto alloc = [&](size_t bytes) -> char* {
        char* p = ws;
        ws += (bytes + 255) / 256 * 256;
        return p;
    };
    int nb = (U + 255) / 256;
    int*    winner = (int*)alloc((size_t)U * 8 * 4);
    int*    bc     = (int*)alloc((size_t)nb * 4);
    int*    sel    = (int*)alloc((size_t)M * 4);
    float*  ss     = (float*)alloc(640 * 4);     // ss1[512] then ss2[128]
    ushort* w1t    = (ushort*)alloc((size_t)512 * 256 * 2);
    ushort* w2t    = (ushort*)alloc((size_t)256 * 64 * 2);
    ushort* xsg    = (ushort*)alloc((size_t)Mp * 512 * 2);
    ushort* y1     = (ushort*)alloc((size_t)Mp * 256 * 2);

    hipMemsetAsync(winner, 0xFF, (size_t)U * 8 * 4, stream);   // -1 (atomicMax floor)

    int npro = (Nv + 255) / 256;
    k_prologue<<<npro, 256, 0, stream>>>(inv, coords, Nv, cnt, U, bc, nb,
                                         bs_w1, bs_w2, w1t, w2t, ss, winner);
    k_write_sel<<<nb, 256, 0, stream>>>(cnt, U, bc, sel);

    int nblk = 2048;                    // 4 waves each -> 8192 waves
    k_feat5<<<nblk, 256, 0, stream>>>(
        vf, winner, sel, up_w1, up_b1, up_w2, up_b2,
        ca_w1, ca_w2, sa_conv, xsg, M, Mp, nblk * 4);

    k_gemm1<<<Mp / 128, 512, 0, stream>>>(xsg, w1t, y1, ss, Mp);

    k_gemm2<<<Mp / 128, 256, 0, stream>>>(y1, w2t, ss, bn1_g, bn1_b,
                                          1.0f / (float)M, out, ss + 512, M);

    int n4 = (M * 64) / 4;
    k_bn2_apply4<<<(n4 + 255) / 256, 256, 0, stream>>>(
        (float4*)out, ss + 512, bn2_g, bn2_b, 1.0f / (float)M, n4);
}